// Round 3
// baseline (1184.345 us; speedup 1.0000x reference)
//
#include <hip/hip_runtime.h>
#include <math.h>

#define BN_EPS 1e-5f

// ---------------------------------------------------------------------------
// Round 3: pipelined convs (1 barrier/k, prefetched gathers), BN fused into
// consumers (no bn_apply passes), min/max pool trick, float4 stats.
// ---------------------------------------------------------------------------

__device__ __forceinline__ void fma4(float s, const float4& w, float4& a) {
    a.x = fmaf(s, w.x, a.x);
    a.y = fmaf(s, w.y, a.y);
    a.z = fmaf(s, w.z, a.z);
    a.w = fmaf(s, w.w, a.w);
}

__device__ __forceinline__ float nlr(float x, float sc, float sh) {
    float t = fmaf(x, sc, sh);
    return fmaxf(t, 0.01f * t);  // leakyrelu(bn): exact for any sign of t
}

__device__ __forceinline__ void bn_coef(const float* __restrict__ sums,
                                        const float* __restrict__ g,
                                        const float* __restrict__ b,
                                        int C, int c, float inv_n,
                                        float& sc, float& sh) {
    float mean = sums[c] * inv_n;
    float var = fmaxf(fmaf(-mean, mean, sums[C + c] * inv_n), 0.f);
    sc = g[c] * rsqrtf(var + BN_EPS);
    sh = fmaf(-mean, sc, b[c]);
}

__global__ void zero_kernel(float* __restrict__ p, int n) {
    int i = blockIdx.x * blockDim.x + threadIdx.x;
    if (i < n) p[i] = 0.f;
}

// mlp1: one thread per row, [N,3]@[3,16] raw
__global__ void mlp1_kernel(const float* __restrict__ x, const float* __restrict__ w,
                            float* __restrict__ out, int N) {
    int n = blockIdx.x * blockDim.x + threadIdx.x;
    if (n >= N) return;
    float x0 = x[n * 3], x1 = x[n * 3 + 1], x2 = x[n * 3 + 2];
    #pragma unroll
    for (int c4 = 0; c4 < 4; c4++) {
        float4 w0 = *reinterpret_cast<const float4*>(w + 0 + c4 * 4);
        float4 w1 = *reinterpret_cast<const float4*>(w + 16 + c4 * 4);
        float4 w2 = *reinterpret_cast<const float4*>(w + 32 + c4 * 4);
        float4 o;
        o.x = fmaf(x0, w0.x, fmaf(x1, w1.x, x2 * w2.x));
        o.y = fmaf(x0, w0.y, fmaf(x1, w1.y, x2 * w2.y));
        o.z = fmaf(x0, w0.z, fmaf(x1, w1.z, x2 * w2.z));
        o.w = fmaf(x0, w0.w, fmaf(x1, w1.w, x2 * w2.w));
        *reinterpret_cast<float4*>(out + n * 16 + c4 * 4) = o;
    }
}

// per-channel sum & sumsq, float4; host guarantees blockDim % C4 == 0
__global__ void stats4_kernel(const float4* __restrict__ x, int total4, int C, int C4,
                              float* __restrict__ sums) {
    __shared__ float ls[1024];
    int tid = threadIdx.x;
    for (int j = tid; j < 2 * C; j += blockDim.x) ls[j] = 0.f;
    __syncthreads();
    int stride = gridDim.x * blockDim.x;
    int i = blockIdx.x * blockDim.x + tid;
    int c4 = i % C4;
    float4 s = make_float4(0.f, 0.f, 0.f, 0.f);
    float4 q = make_float4(0.f, 0.f, 0.f, 0.f);
    for (; i < total4; i += stride) {
        float4 v = x[i];
        s.x += v.x; s.y += v.y; s.z += v.z; s.w += v.w;
        q.x = fmaf(v.x, v.x, q.x); q.y = fmaf(v.y, v.y, q.y);
        q.z = fmaf(v.z, v.z, q.z); q.w = fmaf(v.w, v.w, q.w);
    }
    int cb = c4 * 4;
    atomicAdd(&ls[cb + 0], s.x); atomicAdd(&ls[cb + 1], s.y);
    atomicAdd(&ls[cb + 2], s.z); atomicAdd(&ls[cb + 3], s.w);
    atomicAdd(&ls[C + cb + 0], q.x); atomicAdd(&ls[C + cb + 1], q.y);
    atomicAdd(&ls[C + cb + 2], q.z); atomicAdd(&ls[C + cb + 3], q.w);
    __syncthreads();
    for (int j = tid; j < 2 * C; j += blockDim.x) atomicAdd(&sums[j], ls[j]);
}

// ---------------------------------------------------------------------------
// Pipelined sparse conv: ping-pong LDS staging, 1 barrier per k, prefetch.
// grid (N/TM, COUT/CO_TILE, 27/KT)
// ---------------------------------------------------------------------------
template <int CIN, int COUT, int CO_TILE, int TM, int NTHR, int NQ, int KT,
          bool NORM_IN, bool ATOMIC>
__global__ __launch_bounds__(NTHR) void conv3_kernel(
    const float* __restrict__ y, const int* __restrict__ nbr,
    const float* __restrict__ w, float* __restrict__ out,
    const float* __restrict__ sums, const float* __restrict__ gg,
    const float* __restrict__ bb, float inv_n) {
    constexpr int CQT = CO_TILE / (4 * NQ);
    constexpr int MGRP = NTHR / CQT;
    constexpr int RT = TM / MGRP;
    constexpr int LROW = CIN + 4;
    constexpr int SLOTS = TM * (CIN / 4);
    constexpr int GPT = (SLOTS + NTHR - 1) / NTHR;

    __shared__ __align__(16) float a[2][TM * LROW];
    __shared__ __align__(16) float nsc[CIN], nsh[CIN];

    const int tid = threadIdx.x;
    const int m0 = blockIdx.x * TM;
    const int cobase = blockIdx.y * CO_TILE;
    const int k0 = blockIdx.z * KT;
    const int cq = tid % CQT;
    const int mg = tid / CQT;

    if constexpr (NORM_IN) {
        for (int c = tid; c < CIN; c += NTHR) {
            float sc, sh;
            bn_coef(sums, gg, bb, CIN, c, inv_n, sc, sh);
            nsc[c] = sc;
            nsh[c] = sh;
        }
    }

    int mj[GPT], c4j[GPT];
    bool vj[GPT];
    #pragma unroll
    for (int j = 0; j < GPT; j++) {
        int idx = tid + j * NTHR;
        vj[j] = idx < SLOTS;
        int ii = vj[j] ? idx : 0;
        mj[j] = ii / (CIN / 4);
        c4j[j] = ii % (CIN / 4);
    }

    // prologue: indices(k0) -> gathers(k0) -> indices(k0+1)
    int nidx[GPT];
    #pragma unroll
    for (int j = 0; j < GPT; j++)
        if (vj[j]) nidx[j] = nbr[(m0 + mj[j]) * 27 + k0];
    float4 gv[GPT];
    #pragma unroll
    for (int j = 0; j < GPT; j++)
        if (vj[j]) gv[j] = *reinterpret_cast<const float4*>(
            y + (size_t)nidx[j] * CIN + c4j[j] * 4);
    if (KT > 1) {
        #pragma unroll
        for (int j = 0; j < GPT; j++)
            if (vj[j]) nidx[j] = nbr[(m0 + mj[j]) * 27 + k0 + 1];
    }
    __syncthreads();  // nsc ready
    #pragma unroll
    for (int j = 0; j < GPT; j++) {
        if (!vj[j]) continue;
        float4 v = gv[j];
        if constexpr (NORM_IN) {
            float4 sc = *reinterpret_cast<const float4*>(&nsc[c4j[j] * 4]);
            float4 sh = *reinterpret_cast<const float4*>(&nsh[c4j[j] * 4]);
            v.x = nlr(v.x, sc.x, sh.x); v.y = nlr(v.y, sc.y, sh.y);
            v.z = nlr(v.z, sc.z, sh.z); v.w = nlr(v.w, sc.w, sh.w);
        }
        *reinterpret_cast<float4*>(&a[0][mj[j] * LROW + c4j[j] * 4]) = v;
    }
    __syncthreads();

    float4 acc[RT][NQ];
    #pragma unroll
    for (int r = 0; r < RT; r++)
        #pragma unroll
        for (int q = 0; q < NQ; q++) acc[r][q] = make_float4(0.f, 0.f, 0.f, 0.f);

    for (int kk = 0; kk < KT; kk++) {
        const int cur = kk & 1;
        if (kk + 1 < KT) {
            #pragma unroll
            for (int j = 0; j < GPT; j++)
                if (vj[j]) gv[j] = *reinterpret_cast<const float4*>(
                    y + (size_t)nidx[j] * CIN + c4j[j] * 4);
            if (kk + 2 < KT) {
                #pragma unroll
                for (int j = 0; j < GPT; j++)
                    if (vj[j]) nidx[j] = nbr[(m0 + mj[j]) * 27 + k0 + kk + 2];
            }
        }
        const float* wk = w + (size_t)(k0 + kk) * CIN * COUT + cobase + cq * (4 * NQ);
        const float* ar = &a[cur][mg * LROW];
        #pragma unroll 8
        for (int ci4 = 0; ci4 < CIN / 4; ci4++) {
            float4 wv[4][NQ];
            #pragma unroll
            for (int jj = 0; jj < 4; jj++)
                #pragma unroll
                for (int q = 0; q < NQ; q++)
                    wv[jj][q] = *reinterpret_cast<const float4*>(
                        wk + (size_t)(ci4 * 4 + jj) * COUT + q * 4);
            #pragma unroll
            for (int r = 0; r < RT; r++) {
                float4 av = *reinterpret_cast<const float4*>(&ar[r * MGRP * LROW + ci4 * 4]);
                #pragma unroll
                for (int q = 0; q < NQ; q++) {
                    fma4(av.x, wv[0][q], acc[r][q]);
                    fma4(av.y, wv[1][q], acc[r][q]);
                    fma4(av.z, wv[2][q], acc[r][q]);
                    fma4(av.w, wv[3][q], acc[r][q]);
                }
            }
        }
        if (kk + 1 < KT) {
            #pragma unroll
            for (int j = 0; j < GPT; j++) {
                if (!vj[j]) continue;
                float4 v = gv[j];
                if constexpr (NORM_IN) {
                    float4 sc = *reinterpret_cast<const float4*>(&nsc[c4j[j] * 4]);
                    float4 sh = *reinterpret_cast<const float4*>(&nsh[c4j[j] * 4]);
                    v.x = nlr(v.x, sc.x, sh.x); v.y = nlr(v.y, sc.y, sh.y);
                    v.z = nlr(v.z, sc.z, sh.z); v.w = nlr(v.w, sc.w, sh.w);
                }
                *reinterpret_cast<float4*>(&a[cur ^ 1][mj[j] * LROW + c4j[j] * 4]) = v;
            }
        }
        __syncthreads();
    }

    #pragma unroll
    for (int r = 0; r < RT; r++)
        #pragma unroll
        for (int q = 0; q < NQ; q++) {
            float* op = out + (size_t)(m0 + mg + r * MGRP) * COUT + cobase + (cq * NQ + q) * 4;
            if constexpr (ATOMIC) {
                atomicAdd(op + 0, acc[r][q].x);
                atomicAdd(op + 1, acc[r][q].y);
                atomicAdd(op + 2, acc[r][q].z);
                atomicAdd(op + 3, acc[r][q].w);
            } else {
                *reinterpret_cast<float4*>(op) = acc[r][q];
            }
        }
}

// ---------------------------------------------------------------------------
// down (concat + 1x1): 2 rows x NQ quads per thread, inputs normalized on fly
// ---------------------------------------------------------------------------
template <int C1, int C2, int COUT, int NQ, int NTHR, bool NORM1>
__global__ __launch_bounds__(NTHR) void down3_kernel(
    const float* __restrict__ in1, const float* __restrict__ in2,
    const float* __restrict__ w, float* __restrict__ out,
    const float* __restrict__ s1, const float* __restrict__ g1,
    const float* __restrict__ b1, float inv1,
    const float* __restrict__ s2, const float* __restrict__ g2,
    const float* __restrict__ b2, float inv2) {
    constexpr int CQT = COUT / (4 * NQ);
    constexpr int PAIRS = NTHR / CQT;
    __shared__ __align__(16) float n1c[C1], n1h[C1], n2c[C2], n2h[C2];

    const int tid = threadIdx.x;
    if constexpr (NORM1) {
        for (int c = tid; c < C1; c += NTHR) {
            float sc, sh;
            bn_coef(s1, g1, b1, C1, c, inv1, sc, sh);
            n1c[c] = sc; n1h[c] = sh;
        }
    }
    for (int c = tid; c < C2; c += NTHR) {
        float sc, sh;
        bn_coef(s2, g2, b2, C2, c, inv2, sc, sh);
        n2c[c] = sc; n2h[c] = sh;
    }
    __syncthreads();

    const int cq = tid % CQT;
    const int pr = tid / CQT;
    const int n0 = (blockIdx.x * PAIRS + pr) * 2;

    float4 acc[2][NQ];
    #pragma unroll
    for (int r = 0; r < 2; r++)
        #pragma unroll
        for (int q = 0; q < NQ; q++) acc[r][q] = make_float4(0.f, 0.f, 0.f, 0.f);

    const float* w1 = w + cq * (4 * NQ);
    #pragma unroll 8
    for (int ci4 = 0; ci4 < C1 / 4; ci4++) {
        float4 a0 = *reinterpret_cast<const float4*>(in1 + (size_t)n0 * C1 + ci4 * 4);
        float4 a1 = *reinterpret_cast<const float4*>(in1 + (size_t)(n0 + 1) * C1 + ci4 * 4);
        if constexpr (NORM1) {
            float4 sc = *reinterpret_cast<const float4*>(&n1c[ci4 * 4]);
            float4 sh = *reinterpret_cast<const float4*>(&n1h[ci4 * 4]);
            a0.x = nlr(a0.x, sc.x, sh.x); a0.y = nlr(a0.y, sc.y, sh.y);
            a0.z = nlr(a0.z, sc.z, sh.z); a0.w = nlr(a0.w, sc.w, sh.w);
            a1.x = nlr(a1.x, sc.x, sh.x); a1.y = nlr(a1.y, sc.y, sh.y);
            a1.z = nlr(a1.z, sc.z, sh.z); a1.w = nlr(a1.w, sc.w, sh.w);
        }
        #pragma unroll
        for (int jj = 0; jj < 4; jj++) {
            const float* wp = w1 + (size_t)(ci4 * 4 + jj) * COUT;
            #pragma unroll
            for (int q = 0; q < NQ; q++) {
                float4 wv = *reinterpret_cast<const float4*>(wp + q * 4);
                float e0 = jj == 0 ? a0.x : jj == 1 ? a0.y : jj == 2 ? a0.z : a0.w;
                float e1 = jj == 0 ? a1.x : jj == 1 ? a1.y : jj == 2 ? a1.z : a1.w;
                fma4(e0, wv, acc[0][q]);
                fma4(e1, wv, acc[1][q]);
            }
        }
    }
    const float* w2 = w + (size_t)C1 * COUT + cq * (4 * NQ);
    #pragma unroll 8
    for (int ci4 = 0; ci4 < C2 / 4; ci4++) {
        float4 a0 = *reinterpret_cast<const float4*>(in2 + (size_t)n0 * C2 + ci4 * 4);
        float4 a1 = *reinterpret_cast<const float4*>(in2 + (size_t)(n0 + 1) * C2 + ci4 * 4);
        float4 sc = *reinterpret_cast<const float4*>(&n2c[ci4 * 4]);
        float4 sh = *reinterpret_cast<const float4*>(&n2h[ci4 * 4]);
        a0.x = nlr(a0.x, sc.x, sh.x); a0.y = nlr(a0.y, sc.y, sh.y);
        a0.z = nlr(a0.z, sc.z, sh.z); a0.w = nlr(a0.w, sc.w, sh.w);
        a1.x = nlr(a1.x, sc.x, sh.x); a1.y = nlr(a1.y, sc.y, sh.y);
        a1.z = nlr(a1.z, sc.z, sh.z); a1.w = nlr(a1.w, sc.w, sh.w);
        #pragma unroll
        for (int jj = 0; jj < 4; jj++) {
            const float* wp = w2 + (size_t)(ci4 * 4 + jj) * COUT;
            #pragma unroll
            for (int q = 0; q < NQ; q++) {
                float4 wv = *reinterpret_cast<const float4*>(wp + q * 4);
                float e0 = jj == 0 ? a0.x : jj == 1 ? a0.y : jj == 2 ? a0.z : a0.w;
                float e1 = jj == 0 ? a1.x : jj == 1 ? a1.y : jj == 2 ? a1.z : a1.w;
                fma4(e0, wv, acc[0][q]);
                fma4(e1, wv, acc[1][q]);
            }
        }
    }
    #pragma unroll
    for (int r = 0; r < 2; r++)
        #pragma unroll
        for (int q = 0; q < NQ; q++)
            *reinterpret_cast<float4*>(out + (size_t)(n0 + r) * COUT + cq * (4 * NQ) + q * 4) =
                acc[r][q];
}

// ---------------------------------------------------------------------------
// pool: gather raw down output, min/max over 27, then BN+lrelu by scale sign
// ---------------------------------------------------------------------------
template <int C, int NTHR>
__global__ __launch_bounds__(NTHR) void pool2_kernel(
    const float* __restrict__ draw, const int* __restrict__ pmap,
    const float* __restrict__ sums, const float* __restrict__ g,
    const float* __restrict__ b, float inv_n,
    float* __restrict__ yout, int Nout) {
    constexpr int C4 = C / 4;
    int i = blockIdx.x * NTHR + threadIdx.x;
    if (i >= Nout * C4) return;
    int n = i / C4, c4 = i % C4;
    float sc[4], sh[4];
    #pragma unroll
    for (int j = 0; j < 4; j++) bn_coef(sums, g, b, C, c4 * 4 + j, inv_n, sc[j], sh[j]);
    const int* pm = pmap + n * 27;
    float4 mn = make_float4(INFINITY, INFINITY, INFINITY, INFINITY);
    float4 mx = make_float4(-INFINITY, -INFINITY, -INFINITY, -INFINITY);
    #pragma unroll 9
    for (int k = 0; k < 27; k++) {
        int row = pm[k];
        float4 v = *reinterpret_cast<const float4*>(draw + (size_t)row * C + c4 * 4);
        mn.x = fminf(mn.x, v.x); mn.y = fminf(mn.y, v.y);
        mn.z = fminf(mn.z, v.z); mn.w = fminf(mn.w, v.w);
        mx.x = fmaxf(mx.x, v.x); mx.y = fmaxf(mx.y, v.y);
        mx.z = fmaxf(mx.z, v.z); mx.w = fmaxf(mx.w, v.w);
    }
    float4 o;
    o.x = nlr(sc[0] >= 0.f ? mx.x : mn.x, sc[0], sh[0]);
    o.y = nlr(sc[1] >= 0.f ? mx.y : mn.y, sc[1], sh[1]);
    o.z = nlr(sc[2] >= 0.f ? mx.z : mn.z, sc[2], sh[2]);
    o.w = nlr(sc[3] >= 0.f ? mx.w : mn.w, sc[3], sh[3]);
    *reinterpret_cast<float4*>(yout + (size_t)n * C + c4 * 4) = o;
}

// segment pooling over conv6 raw: max (min/max trick) || mean of normalized
__global__ void segpool2_kernel(const float* __restrict__ y,
                                const float* __restrict__ sums,
                                const float* __restrict__ g, const float* __restrict__ b,
                                float inv_n, float* __restrict__ z) {
    int bi = blockIdx.x;
    int c = threadIdx.x;  // 512
    float sc, sh;
    bn_coef(sums, g, b, 512, c, inv_n, sc, sh);
    float mn = INFINITY, mx = -INFINITY, sm = 0.f;
    for (int r = 0; r < 32; r++) {
        float v = y[(size_t)(bi * 32 + r) * 512 + c];
        mn = fminf(mn, v);
        mx = fmaxf(mx, v);
        sm += nlr(v, sc, sh);
    }
    z[bi * 1024 + c] = nlr(sc >= 0.f ? mx : mn, sc, sh);
    z[bi * 1024 + 512 + c] = sm * (1.f / 32.f);
}

// FC (M=8): grid (COUT/64, KSPLIT); optional input normalization at staging
template <int K, int COUT, int KSPLIT, bool NORM>
__global__ __launch_bounds__(256) void fc_kernel(
    const float* __restrict__ z, const float* __restrict__ w,
    const float* __restrict__ ns, const float* __restrict__ ng,
    const float* __restrict__ nb, float inv_n,
    float* __restrict__ out) {
    constexpr int KC = K / KSPLIT;
    constexpr int KG = KC / 16;
    __shared__ __align__(16) float zt[KC * 8];
    __shared__ float red[16 * 520];

    const int cobase = blockIdx.x * 64;
    const int kc0 = blockIdx.y * KC;
    const int tid = threadIdx.x;
    const int coq = tid & 15;
    const int kg = tid >> 4;

    for (int idx = tid; idx < 8 * (KC / 4); idx += 256) {
        int n = idx / (KC / 4);
        int kq = idx - n * (KC / 4);
        float4 v = *reinterpret_cast<const float4*>(z + (size_t)n * K + kc0 + kq * 4);
        if constexpr (NORM) {
            #pragma unroll
            for (int j = 0; j < 4; j++) {
                float sc, sh;
                bn_coef(ns, ng, nb, K, kc0 + kq * 4 + j, inv_n, sc, sh);
                float* pv = j == 0 ? &v.x : j == 1 ? &v.y : j == 2 ? &v.z : &v.w;
                *pv = nlr(*pv, sc, sh);
            }
        }
        zt[(kq * 4 + 0) * 8 + n] = v.x;
        zt[(kq * 4 + 1) * 8 + n] = v.y;
        zt[(kq * 4 + 2) * 8 + n] = v.z;
        zt[(kq * 4 + 3) * 8 + n] = v.w;
    }
    __syncthreads();

    float4 acc[8];
    #pragma unroll
    for (int n = 0; n < 8; n++) acc[n] = make_float4(0.f, 0.f, 0.f, 0.f);
    for (int ki = 0; ki < KG; ki++) {
        int k = kg * KG + ki;
        float4 wv = *reinterpret_cast<const float4*>(
            w + (size_t)(kc0 + k) * COUT + cobase + coq * 4);
        float4 za = *reinterpret_cast<const float4*>(&zt[k * 8]);
        float4 zb = *reinterpret_cast<const float4*>(&zt[k * 8 + 4]);
        fma4(za.x, wv, acc[0]); fma4(za.y, wv, acc[1]);
        fma4(za.z, wv, acc[2]); fma4(za.w, wv, acc[3]);
        fma4(zb.x, wv, acc[4]); fma4(zb.y, wv, acc[5]);
        fma4(zb.z, wv, acc[6]); fma4(zb.w, wv, acc[7]);
    }
    #pragma unroll
    for (int n = 0; n < 8; n++) {
        red[kg * 520 + (coq * 4 + 0) * 8 + n] = acc[n].x;
        red[kg * 520 + (coq * 4 + 1) * 8 + n] = acc[n].y;
        red[kg * 520 + (coq * 4 + 2) * 8 + n] = acc[n].z;
        red[kg * 520 + (coq * 4 + 3) * 8 + n] = acc[n].w;
    }
    __syncthreads();
    for (int oi = tid; oi < 512; oi += 256) {
        int c = oi >> 3;
        int n = oi & 7;
        float s = 0.f;
        #pragma unroll
        for (int gg = 0; gg < 16; gg++) s += red[gg * 520 + c * 8 + n];
        float* op = out + (size_t)n * COUT + cobase + c;
        if (KSPLIT > 1) atomicAdd(op, s);
        else *op = s;
    }
}

// f3: normalize f2 raw into LDS, then [8,256]@[256,20]+bias
__global__ void f3n_kernel(const float* __restrict__ in, const float* __restrict__ w,
                           const float* __restrict__ bias,
                           const float* __restrict__ sums, const float* __restrict__ g,
                           const float* __restrict__ b, float inv_n,
                           float* __restrict__ out) {
    __shared__ float zin[8 * 256];
    int tid = threadIdx.x;  // 256
    for (int idx = tid; idx < 2048; idx += 256) {
        int c = idx & 255;
        float sc, sh;
        bn_coef(sums, g, b, 256, c, inv_n, sc, sh);
        zin[idx] = nlr(in[idx], sc, sh);
    }
    __syncthreads();
    if (tid >= 160) return;
    int n = tid / 20, co = tid % 20;
    float acc = bias[co];
    for (int ci = 0; ci < 256; ci++)
        acc = fmaf(zin[n * 256 + ci], w[ci * 20 + co], acc);
    out[tid] = acc;
}

// ---------------------------------------------------------------------------

extern "C" void kernel_launch(void* const* d_in, const int* in_sizes, int n_in,
                              void* d_out, int out_size, void* d_ws, size_t ws_size,
                              hipStream_t stream) {
    (void)in_sizes; (void)n_in; (void)out_size; (void)ws_size;

    const int N0 = 131072, N1 = 32768, N2 = 8192, N3 = 2048, N4 = 512, N5 = 256;

    const float* x      = (const float*)d_in[0];
    const float* w_mlp1 = (const float*)d_in[1];
    const float* g_mlp1 = (const float*)d_in[2];
    const float* b_mlp1 = (const float*)d_in[3];
    const float* w_c[6]; const float* g_c[6]; const float* b_c[6];
    for (int i = 0; i < 6; i++) {
        w_c[i] = (const float*)d_in[4 + 3 * i];
        g_c[i] = (const float*)d_in[5 + 3 * i];
        b_c[i] = (const float*)d_in[6 + 3 * i];
    }
    const float* w_d[5]; const float* g_d[5]; const float* b_d[5];
    for (int i = 0; i < 5; i++) {
        w_d[i] = (const float*)d_in[22 + 3 * i];
        g_d[i] = (const float*)d_in[23 + 3 * i];
        b_d[i] = (const float*)d_in[24 + 3 * i];
    }
    const float* w_f1 = (const float*)d_in[37];
    const float* g_f1 = (const float*)d_in[38];
    const float* b_f1 = (const float*)d_in[39];
    const float* w_f2 = (const float*)d_in[40];
    const float* g_f2 = (const float*)d_in[41];
    const float* b_f2 = (const float*)d_in[42];
    const float* w_f3 = (const float*)d_in[43];
    const float* bias_f3 = (const float*)d_in[44];
    const int* nbr[6];
    for (int i = 0; i < 6; i++) nbr[i] = (const int*)d_in[45 + i];
    const int* pool[5];
    for (int i = 0; i < 5; i++) pool[i] = (const int*)d_in[51 + i];

    float* ws    = (float*)d_ws;
    float* bufA  = ws;                    // y / fc1 out
    float* bufB  = bufA + 2097152;        // conv raw / fc2 out
    float* bufC  = bufB + 4194304;        // down raw / z
    float* stats = bufC + 4194304;        // 14 * 1024
    float* out = (float*)d_out;

    auto st = [&](int slot) { return stats + slot * 1024; };
    auto run_stats = [&](const float* buf, int total, int C, int bs, int slot) {
        int total4 = total / 4, C4 = C / 4;
        int gr = (total4 + bs - 1) / bs;
        if (gr > 768) gr = 768;
        stats4_kernel<<<gr, bs, 0, stream>>>((const float4*)buf, total4, C, C4, st(slot));
    };

    const float iN0 = 1.f / N0, iN1 = 1.f / N1, iN2 = 1.f / N2, iN3 = 1.f / N3,
                iN4 = 1.f / N4, iN5 = 1.f / N5, i8 = 1.f / 8.f;

    zero_kernel<<<56, 256, 0, stream>>>(stats, 14 * 1024);

    // ---- mlp1 raw -> bufA
    mlp1_kernel<<<N0 / 256, 256, 0, stream>>>(x, w_mlp1, bufA, N0);
    run_stats(bufA, N0 * 16, 16, 256, 0);

    // ---- level 0
    conv3_kernel<16, 32, 32, 128, 256, 2, 27, true, false>
        <<<dim3(N0 / 128, 1, 1), 256, 0, stream>>>(bufA, nbr[0], w_c[0], bufB,
                                                   st(0), g_mlp1, b_mlp1, iN0);
    run_stats(bufB, N0 * 32, 32, 256, 1);
    down3_kernel<16, 32, 32, 2, 256, true>
        <<<1024, 256, 0, stream>>>(bufA, bufB, w_d[0], bufC,
                                   st(0), g_mlp1, b_mlp1, iN0, st(1), g_c[0], b_c[0], iN0);
    run_stats(bufC, N0 * 32, 32, 256, 2);
    pool2_kernel<32, 256><<<N1 * 8 / 256, 256, 0, stream>>>(
        bufC, pool[0], st(2), g_d[0], b_d[0], iN0, bufA, N1);

    // ---- level 1
    conv3_kernel<32, 48, 48, 64, 192, 2, 27, false, false>
        <<<dim3(N1 / 64, 1, 1), 192, 0, stream>>>(bufA, nbr[1], w_c[1], bufB,
                                                  nullptr, nullptr, nullptr, 0.f);
    run_stats(bufB, N1 * 48, 48, 192, 3);
    down3_kernel<32, 48, 48, 2, 192, false>
        <<<512, 192, 0, stream>>>(bufA, bufB, w_d[1], bufC,
                                  nullptr, nullptr, nullptr, 0.f, st(3), g_c[1], b_c[1], iN1);
    run_stats(bufC, N1 * 48, 48, 192, 4);
    pool2_kernel<48, 192><<<N2 * 12 / 192, 192, 0, stream>>>(
        bufC, pool[1], st(4), g_d[1], b_d[1], iN1, bufA, N2);

    // ---- level 2
    conv3_kernel<48, 96, 48, 64, 192, 2, 27, false, false>
        <<<dim3(N2 / 64, 2, 1), 192, 0, stream>>>(bufA, nbr[2], w_c[2], bufB,
                                                  nullptr, nullptr, nullptr, 0.f);
    run_stats(bufB, N2 * 96, 96, 192, 5);
    down3_kernel<48, 96, 96, 2, 192, false>
        <<<256, 192, 0, stream>>>(bufA, bufB, w_d[2], bufC,
                                  nullptr, nullptr, nullptr, 0.f, st(5), g_c[2], b_c[2], iN2);
    run_stats(bufC, N2 * 96, 96, 192, 6);
    pool2_kernel<96, 192><<<N3 * 24 / 192, 192, 0, stream>>>(
        bufC, pool[2], st(6), g_d[2], b_d[2], iN2, bufA, N3);

    // ---- level 3 (split-k conv, atomic)
    zero_kernel<<<N3 * 128 / 256, 256, 0, stream>>>(bufB, N3 * 128);
    conv3_kernel<96, 128, 64, 64, 256, 2, 9, false, true>
        <<<dim3(N3 / 64, 2, 3), 256, 0, stream>>>(bufA, nbr[3], w_c[3], bufB,
                                                  nullptr, nullptr, nullptr, 0.f);
    run_stats(bufB, N3 * 128, 128, 256, 7);
    down3_kernel<96, 128, 128, 2, 256, false>
        <<<64, 256, 0, stream>>>(bufA, bufB, w_d[3], bufC,
                                 nullptr, nullptr, nullptr, 0.f, st(7), g_c[3], b_c[3], iN3);
    run_stats(bufC, N3 * 128, 128, 256, 8);
    pool2_kernel<128, 256><<<N4 * 32 / 256, 256, 0, stream>>>(
        bufC, pool[3], st(8), g_d[3], b_d[3], iN3, bufA, N4);

    // ---- level 4
    zero_kernel<<<N4 * 256 / 256, 256, 0, stream>>>(bufB, N4 * 256);
    conv3_kernel<128, 256, 64, 32, 128, 2, 3, false, true>
        <<<dim3(N4 / 32, 4, 9), 128, 0, stream>>>(bufA, nbr[4], w_c[4], bufB,
                                                  nullptr, nullptr, nullptr, 0.f);
    run_stats(bufB, N4 * 256, 256, 256, 9);
    down3_kernel<128, 256, 256, 2, 256, false>
        <<<32, 256, 0, stream>>>(bufA, bufB, w_d[4], bufC,
                                 nullptr, nullptr, nullptr, 0.f, st(9), g_c[4], b_c[4], iN4);
    run_stats(bufC, N4 * 256, 256, 256, 10);
    pool2_kernel<256, 256><<<N5 * 64 / 256, 256, 0, stream>>>(
        bufC, pool[4], st(10), g_d[4], b_d[4], iN4, bufA, N5);

    // ---- conv6 (split-k, atomic)
    zero_kernel<<<N5 * 512 / 256, 256, 0, stream>>>(bufB, N5 * 512);
    conv3_kernel<256, 512, 64, 16, 128, 1, 3, false, true>
        <<<dim3(N5 / 16, 8, 9), 128, 0, stream>>>(bufA, nbr[5], w_c[5], bufB,
                                                  nullptr, nullptr, nullptr, 0.f);
    run_stats(bufB, N5 * 512, 512, 256, 11);

    // ---- segment pooling (applies conv6 BN) -> z in bufC
    segpool2_kernel<<<8, 512, 0, stream>>>(bufB, st(11), g_c[5], b_c[5], iN5, bufC);

    // ---- f1: z @ w_f1 raw -> bufA
    zero_kernel<<<16, 256, 0, stream>>>(bufA, 4096);
    fc_kernel<1024, 512, 4, false><<<dim3(8, 4), 256, 0, stream>>>(
        bufC, w_f1, nullptr, nullptr, nullptr, 0.f, bufA);
    run_stats(bufA, 8 * 512, 512, 256, 12);

    // ---- f2: normalize(f1) @ w_f2 raw -> bufB
    zero_kernel<<<8, 256, 0, stream>>>(bufB, 2048);
    fc_kernel<512, 256, 4, true><<<dim3(4, 4), 256, 0, stream>>>(
        bufA, w_f2, st(12), g_f1, b_f1, i8, bufB);
    run_stats(bufB, 8 * 256, 256, 256, 13);

    // ---- f3
    f3n_kernel<<<1, 256, 0, stream>>>(bufB, w_f3, bias_f3, st(13), g_f2, b_f2, i8, out);
}

// Round 4
// 1148.497 us; speedup vs baseline: 1.0312x; 1.0312x over previous
//
#include <hip/hip_runtime.h>
#include <math.h>

#define BN_EPS 1e-5f

// ---------------------------------------------------------------------------
// Round 4: direct (no-LDS) convs with XCD co-slicing, k-split via partial
// buffers + fused reduce/stats kernel, BN stats fused into conv/down.
// ---------------------------------------------------------------------------

__device__ __forceinline__ void fma4(float s, const float4& w, float4& a) {
    a.x = fmaf(s, w.x, a.x);
    a.y = fmaf(s, w.y, a.y);
    a.z = fmaf(s, w.z, a.z);
    a.w = fmaf(s, w.w, a.w);
}

__device__ __forceinline__ float nlr(float x, float sc, float sh) {
    float t = fmaf(x, sc, sh);
    return fmaxf(t, 0.01f * t);
}

__device__ __forceinline__ void bn_coef(const float* __restrict__ sums,
                                        const float* __restrict__ g,
                                        const float* __restrict__ b,
                                        int C, int c, float inv_n,
                                        float& sc, float& sh) {
    float mean = sums[c] * inv_n;
    float var = fmaxf(fmaf(-mean, mean, sums[C + c] * inv_n), 0.f);
    sc = g[c] * rsqrtf(var + BN_EPS);
    sh = fmaf(-mean, sc, b[c]);
}

__global__ void zero_kernel(float* __restrict__ p, int n) {
    int i = blockIdx.x * blockDim.x + threadIdx.x;
    if (i < n) p[i] = 0.f;
}

// mlp1: one thread per row, [N,3]@[3,16] raw
__global__ void mlp1_kernel(const float* __restrict__ x, const float* __restrict__ w,
                            float* __restrict__ out, int N) {
    int n = blockIdx.x * blockDim.x + threadIdx.x;
    if (n >= N) return;
    float x0 = x[n * 3], x1 = x[n * 3 + 1], x2 = x[n * 3 + 2];
    #pragma unroll
    for (int c4 = 0; c4 < 4; c4++) {
        float4 w0 = *reinterpret_cast<const float4*>(w + 0 + c4 * 4);
        float4 w1 = *reinterpret_cast<const float4*>(w + 16 + c4 * 4);
        float4 w2 = *reinterpret_cast<const float4*>(w + 32 + c4 * 4);
        float4 o;
        o.x = fmaf(x0, w0.x, fmaf(x1, w1.x, x2 * w2.x));
        o.y = fmaf(x0, w0.y, fmaf(x1, w1.y, x2 * w2.y));
        o.z = fmaf(x0, w0.z, fmaf(x1, w1.z, x2 * w2.z));
        o.w = fmaf(x0, w0.w, fmaf(x1, w1.w, x2 * w2.w));
        *reinterpret_cast<float4*>(out + n * 16 + c4 * 4) = o;
    }
}

// per-channel sum & sumsq, float4; requires blockDim % C4 == 0
__global__ void stats4_kernel(const float4* __restrict__ x, int total4, int C, int C4,
                              float* __restrict__ sums) {
    __shared__ float ls[1024];
    int tid = threadIdx.x;
    for (int j = tid; j < 2 * C; j += blockDim.x) ls[j] = 0.f;
    __syncthreads();
    int stride = gridDim.x * blockDim.x;
    int i = blockIdx.x * blockDim.x + tid;
    int c4 = i % C4;
    float4 s = make_float4(0.f, 0.f, 0.f, 0.f);
    float4 q = make_float4(0.f, 0.f, 0.f, 0.f);
    for (; i < total4; i += stride) {
        float4 v = x[i];
        s.x += v.x; s.y += v.y; s.z += v.z; s.w += v.w;
        q.x = fmaf(v.x, v.x, q.x); q.y = fmaf(v.y, v.y, q.y);
        q.z = fmaf(v.z, v.z, q.z); q.w = fmaf(v.w, v.w, q.w);
    }
    int cb = c4 * 4;
    atomicAdd(&ls[cb + 0], s.x); atomicAdd(&ls[cb + 1], s.y);
    atomicAdd(&ls[cb + 2], s.z); atomicAdd(&ls[cb + 3], s.w);
    atomicAdd(&ls[C + cb + 0], q.x); atomicAdd(&ls[C + cb + 1], q.y);
    atomicAdd(&ls[C + cb + 2], q.z); atomicAdd(&ls[C + cb + 3], q.w);
    __syncthreads();
    for (int j = tid; j < 2 * C; j += blockDim.x) atomicAdd(&sums[j], ls[j]);
}

// reduce KS k-split partial slices + write final + fused stats
// requires blockDim % (C/4) == 0
template <int C, int KS>
__global__ __launch_bounds__(256) void reducek_kernel(
    const float4* __restrict__ in, float4* __restrict__ out, int total4,
    float* __restrict__ sums) {
    __shared__ float ls[1024];
    constexpr int C4 = C / 4;
    int tid = threadIdx.x;
    for (int j = tid; j < 2 * C; j += blockDim.x) ls[j] = 0.f;
    __syncthreads();
    int stride = gridDim.x * blockDim.x;
    int i = blockIdx.x * blockDim.x + tid;
    int c4 = i % C4;
    float4 s = make_float4(0.f, 0.f, 0.f, 0.f);
    float4 q = make_float4(0.f, 0.f, 0.f, 0.f);
    for (; i < total4; i += stride) {
        float4 v = make_float4(0.f, 0.f, 0.f, 0.f);
        #pragma unroll
        for (int p = 0; p < KS; p++) {
            float4 t = in[(size_t)p * total4 + i];
            v.x += t.x; v.y += t.y; v.z += t.z; v.w += t.w;
        }
        out[i] = v;
        s.x += v.x; s.y += v.y; s.z += v.z; s.w += v.w;
        q.x = fmaf(v.x, v.x, q.x); q.y = fmaf(v.y, v.y, q.y);
        q.z = fmaf(v.z, v.z, q.z); q.w = fmaf(v.w, v.w, q.w);
    }
    int cb = c4 * 4;
    atomicAdd(&ls[cb + 0], s.x); atomicAdd(&ls[cb + 1], s.y);
    atomicAdd(&ls[cb + 2], s.z); atomicAdd(&ls[cb + 3], s.w);
    atomicAdd(&ls[C + cb + 0], q.x); atomicAdd(&ls[C + cb + 1], q.y);
    atomicAdd(&ls[C + cb + 2], q.z); atomicAdd(&ls[C + cb + 3], q.w);
    __syncthreads();
    for (int j = tid; j < 2 * C; j += blockDim.x) atomicAdd(&sums[j], ls[j]);
}

// ---------------------------------------------------------------------------
// Direct sparse conv (no LDS staging). 1-D grid = NCOT * MT * KS.
// bid -> (cot, mt, ks); each thread: RT rows x NQ co-quads; rows read straight
// from global (L1 broadcast within block, L2 across blocks); weights streamed
// float4 (L2-resident per-XCD co-slice). k-split writes partial slices.
// ---------------------------------------------------------------------------
template <int CIN, int COUT, int CO_TILE, int NCOT, int MT, int TM, int NTHR,
          int NQ, int KT, bool NORM_IN, bool STATS>
__global__ __launch_bounds__(NTHR) void convd_kernel(
    const float* __restrict__ y, const int* __restrict__ nbr,
    const float* __restrict__ w, float* __restrict__ out,
    const float* __restrict__ s_in, const float* __restrict__ g_in,
    const float* __restrict__ b_in, float inv_n,
    float* __restrict__ s_out) {
    constexpr int CQT = CO_TILE / (4 * NQ);
    constexpr int MGRP = NTHR / CQT;
    constexpr int RT = TM / MGRP;
    static_assert(MGRP * RT == TM, "tile mismatch");

    __shared__ float nsc[NORM_IN ? CIN : 1];
    __shared__ float nsh[NORM_IN ? CIN : 1];
    __shared__ float sred[STATS ? 2 * CO_TILE : 1];

    const int tid = threadIdx.x;
    const int bid = blockIdx.x;
    const int cot = bid % NCOT;
    const int rest = bid / NCOT;
    const int mt = rest % MT;
    const int ks = rest / MT;
    const int m0 = mt * TM;
    const int cobase = cot * CO_TILE;
    const int k0 = ks * KT;
    const int cq = tid % CQT;
    const int mg = tid / CQT;

    if constexpr (NORM_IN) {
        for (int c = tid; c < CIN; c += NTHR) {
            float sc, sh;
            bn_coef(s_in, g_in, b_in, CIN, c, inv_n, sc, sh);
            nsc[c] = sc;
            nsh[c] = sh;
        }
        __syncthreads();
    }

    int mrow[RT];
    #pragma unroll
    for (int r = 0; r < RT; r++) mrow[r] = m0 + mg + r * MGRP;

    float4 acc[RT][NQ];
    #pragma unroll
    for (int r = 0; r < RT; r++)
        #pragma unroll
        for (int q = 0; q < NQ; q++) acc[r][q] = make_float4(0.f, 0.f, 0.f, 0.f);

    for (int kk = k0; kk < k0 + KT; kk++) {
        int rows[RT];
        #pragma unroll
        for (int r = 0; r < RT; r++) rows[r] = nbr[(size_t)mrow[r] * 27 + kk];
        const float* wk = w + (size_t)kk * CIN * COUT + cobase + cq * (4 * NQ);
        #pragma unroll 4
        for (int ci4 = 0; ci4 < CIN / 4; ci4++) {
            float4 yv[RT];
            #pragma unroll
            for (int r = 0; r < RT; r++)
                yv[r] = *reinterpret_cast<const float4*>(
                    y + (size_t)rows[r] * CIN + ci4 * 4);
            if constexpr (NORM_IN) {
                float4 sc = *reinterpret_cast<const float4*>(&nsc[ci4 * 4]);
                float4 sh = *reinterpret_cast<const float4*>(&nsh[ci4 * 4]);
                #pragma unroll
                for (int r = 0; r < RT; r++) {
                    yv[r].x = nlr(yv[r].x, sc.x, sh.x);
                    yv[r].y = nlr(yv[r].y, sc.y, sh.y);
                    yv[r].z = nlr(yv[r].z, sc.z, sh.z);
                    yv[r].w = nlr(yv[r].w, sc.w, sh.w);
                }
            }
            #pragma unroll
            for (int jj = 0; jj < 4; jj++) {
                #pragma unroll
                for (int q = 0; q < NQ; q++) {
                    float4 wv = *reinterpret_cast<const float4*>(
                        wk + (size_t)(ci4 * 4 + jj) * COUT + q * 4);
                    #pragma unroll
                    for (int r = 0; r < RT; r++) {
                        float e = jj == 0 ? yv[r].x : jj == 1 ? yv[r].y
                                 : jj == 2 ? yv[r].z : yv[r].w;
                        fma4(e, wv, acc[r][q]);
                    }
                }
            }
        }
    }

    float* outp = out + (size_t)ks * MT * TM * COUT;
    #pragma unroll
    for (int r = 0; r < RT; r++)
        #pragma unroll
        for (int q = 0; q < NQ; q++)
            *reinterpret_cast<float4*>(
                outp + (size_t)mrow[r] * COUT + cobase + cq * (4 * NQ) + q * 4) =
                acc[r][q];

    if constexpr (STATS) {
        for (int j = tid; j < 2 * CO_TILE; j += NTHR) sred[j] = 0.f;
        __syncthreads();
        #pragma unroll
        for (int q = 0; q < NQ; q++) {
            float4 s = make_float4(0.f, 0.f, 0.f, 0.f);
            float4 qq = make_float4(0.f, 0.f, 0.f, 0.f);
            #pragma unroll
            for (int r = 0; r < RT; r++) {
                float4 v = acc[r][q];
                s.x += v.x; s.y += v.y; s.z += v.z; s.w += v.w;
                qq.x = fmaf(v.x, v.x, qq.x); qq.y = fmaf(v.y, v.y, qq.y);
                qq.z = fmaf(v.z, v.z, qq.z); qq.w = fmaf(v.w, v.w, qq.w);
            }
            int cb = cq * (4 * NQ) + q * 4;
            atomicAdd(&sred[cb + 0], s.x); atomicAdd(&sred[cb + 1], s.y);
            atomicAdd(&sred[cb + 2], s.z); atomicAdd(&sred[cb + 3], s.w);
            atomicAdd(&sred[CO_TILE + cb + 0], qq.x);
            atomicAdd(&sred[CO_TILE + cb + 1], qq.y);
            atomicAdd(&sred[CO_TILE + cb + 2], qq.z);
            atomicAdd(&sred[CO_TILE + cb + 3], qq.w);
        }
        __syncthreads();
        for (int j = tid; j < CO_TILE; j += NTHR) {
            atomicAdd(&s_out[cobase + j], sred[j]);
            atomicAdd(&s_out[COUT + cobase + j], sred[CO_TILE + j]);
        }
    }
}

// ---------------------------------------------------------------------------
// down (concat + 1x1) with fused stats; inputs normalized on the fly.
// ---------------------------------------------------------------------------
template <int C1, int C2, int COUT, int NQ, int NTHR, bool NORM1>
__global__ __launch_bounds__(NTHR) void down3_kernel(
    const float* __restrict__ in1, const float* __restrict__ in2,
    const float* __restrict__ w, float* __restrict__ out,
    const float* __restrict__ s1, const float* __restrict__ g1,
    const float* __restrict__ b1, float inv1,
    const float* __restrict__ s2, const float* __restrict__ g2,
    const float* __restrict__ b2, float inv2,
    float* __restrict__ s_out) {
    constexpr int CQT = COUT / (4 * NQ);
    constexpr int PAIRS = NTHR / CQT;
    __shared__ __align__(16) float n1c[C1], n1h[C1], n2c[C2], n2h[C2];
    __shared__ float sred[2 * COUT];

    const int tid = threadIdx.x;
    if constexpr (NORM1) {
        for (int c = tid; c < C1; c += NTHR) {
            float sc, sh;
            bn_coef(s1, g1, b1, C1, c, inv1, sc, sh);
            n1c[c] = sc; n1h[c] = sh;
        }
    }
    for (int c = tid; c < C2; c += NTHR) {
        float sc, sh;
        bn_coef(s2, g2, b2, C2, c, inv2, sc, sh);
        n2c[c] = sc; n2h[c] = sh;
    }
    for (int j = tid; j < 2 * COUT; j += NTHR) sred[j] = 0.f;
    __syncthreads();

    const int cq = tid % CQT;
    const int pr = tid / CQT;
    const int n0 = (blockIdx.x * PAIRS + pr) * 2;

    float4 acc[2][NQ];
    #pragma unroll
    for (int r = 0; r < 2; r++)
        #pragma unroll
        for (int q = 0; q < NQ; q++) acc[r][q] = make_float4(0.f, 0.f, 0.f, 0.f);

    const float* w1 = w + cq * (4 * NQ);
    #pragma unroll 8
    for (int ci4 = 0; ci4 < C1 / 4; ci4++) {
        float4 a0 = *reinterpret_cast<const float4*>(in1 + (size_t)n0 * C1 + ci4 * 4);
        float4 a1 = *reinterpret_cast<const float4*>(in1 + (size_t)(n0 + 1) * C1 + ci4 * 4);
        if constexpr (NORM1) {
            float4 sc = *reinterpret_cast<const float4*>(&n1c[ci4 * 4]);
            float4 sh = *reinterpret_cast<const float4*>(&n1h[ci4 * 4]);
            a0.x = nlr(a0.x, sc.x, sh.x); a0.y = nlr(a0.y, sc.y, sh.y);
            a0.z = nlr(a0.z, sc.z, sh.z); a0.w = nlr(a0.w, sc.w, sh.w);
            a1.x = nlr(a1.x, sc.x, sh.x); a1.y = nlr(a1.y, sc.y, sh.y);
            a1.z = nlr(a1.z, sc.z, sh.z); a1.w = nlr(a1.w, sc.w, sh.w);
        }
        #pragma unroll
        for (int jj = 0; jj < 4; jj++) {
            const float* wp = w1 + (size_t)(ci4 * 4 + jj) * COUT;
            float e0 = jj == 0 ? a0.x : jj == 1 ? a0.y : jj == 2 ? a0.z : a0.w;
            float e1 = jj == 0 ? a1.x : jj == 1 ? a1.y : jj == 2 ? a1.z : a1.w;
            #pragma unroll
            for (int q = 0; q < NQ; q++) {
                float4 wv = *reinterpret_cast<const float4*>(wp + q * 4);
                fma4(e0, wv, acc[0][q]);
                fma4(e1, wv, acc[1][q]);
            }
        }
    }
    const float* w2 = w + (size_t)C1 * COUT + cq * (4 * NQ);
    #pragma unroll 8
    for (int ci4 = 0; ci4 < C2 / 4; ci4++) {
        float4 a0 = *reinterpret_cast<const float4*>(in2 + (size_t)n0 * C2 + ci4 * 4);
        float4 a1 = *reinterpret_cast<const float4*>(in2 + (size_t)(n0 + 1) * C2 + ci4 * 4);
        float4 sc = *reinterpret_cast<const float4*>(&n2c[ci4 * 4]);
        float4 sh = *reinterpret_cast<const float4*>(&n2h[ci4 * 4]);
        a0.x = nlr(a0.x, sc.x, sh.x); a0.y = nlr(a0.y, sc.y, sh.y);
        a0.z = nlr(a0.z, sc.z, sh.z); a0.w = nlr(a0.w, sc.w, sh.w);
        a1.x = nlr(a1.x, sc.x, sh.x); a1.y = nlr(a1.y, sc.y, sh.y);
        a1.z = nlr(a1.z, sc.z, sh.z); a1.w = nlr(a1.w, sc.w, sh.w);
        #pragma unroll
        for (int jj = 0; jj < 4; jj++) {
            const float* wp = w2 + (size_t)(ci4 * 4 + jj) * COUT;
            float e0 = jj == 0 ? a0.x : jj == 1 ? a0.y : jj == 2 ? a0.z : a0.w;
            float e1 = jj == 0 ? a1.x : jj == 1 ? a1.y : jj == 2 ? a1.z : a1.w;
            #pragma unroll
            for (int q = 0; q < NQ; q++) {
                float4 wv = *reinterpret_cast<const float4*>(wp + q * 4);
                fma4(e0, wv, acc[0][q]);
                fma4(e1, wv, acc[1][q]);
            }
        }
    }
    #pragma unroll
    for (int r = 0; r < 2; r++)
        #pragma unroll
        for (int q = 0; q < NQ; q++)
            *reinterpret_cast<float4*>(out + (size_t)(n0 + r) * COUT + cq * (4 * NQ) + q * 4) =
                acc[r][q];

    // fused stats
    #pragma unroll
    for (int q = 0; q < NQ; q++) {
        float4 s = make_float4(0.f, 0.f, 0.f, 0.f);
        float4 qq = make_float4(0.f, 0.f, 0.f, 0.f);
        #pragma unroll
        for (int r = 0; r < 2; r++) {
            float4 v = acc[r][q];
            s.x += v.x; s.y += v.y; s.z += v.z; s.w += v.w;
            qq.x = fmaf(v.x, v.x, qq.x); qq.y = fmaf(v.y, v.y, qq.y);
            qq.z = fmaf(v.z, v.z, qq.z); qq.w = fmaf(v.w, v.w, qq.w);
        }
        int cb = cq * (4 * NQ) + q * 4;
        atomicAdd(&sred[cb + 0], s.x); atomicAdd(&sred[cb + 1], s.y);
        atomicAdd(&sred[cb + 2], s.z); atomicAdd(&sred[cb + 3], s.w);
        atomicAdd(&sred[COUT + cb + 0], qq.x);
        atomicAdd(&sred[COUT + cb + 1], qq.y);
        atomicAdd(&sred[COUT + cb + 2], qq.z);
        atomicAdd(&sred[COUT + cb + 3], qq.w);
    }
    __syncthreads();
    for (int j = tid; j < COUT; j += NTHR) {
        atomicAdd(&s_out[j], sred[j]);
        atomicAdd(&s_out[COUT + j], sred[COUT + j]);
    }
}

// ---------------------------------------------------------------------------
// pool: gather raw down output, min/max over 27, then BN+lrelu by scale sign
// ---------------------------------------------------------------------------
template <int C, int NTHR>
__global__ __launch_bounds__(NTHR) void pool2_kernel(
    const float* __restrict__ draw, const int* __restrict__ pmap,
    const float* __restrict__ sums, const float* __restrict__ g,
    const float* __restrict__ b, float inv_n,
    float* __restrict__ yout, int Nout) {
    constexpr int C4 = C / 4;
    int i = blockIdx.x * NTHR + threadIdx.x;
    if (i >= Nout * C4) return;
    int n = i / C4, c4 = i % C4;
    float sc[4], sh[4];
    #pragma unroll
    for (int j = 0; j < 4; j++) bn_coef(sums, g, b, C, c4 * 4 + j, inv_n, sc[j], sh[j]);
    const int* pm = pmap + n * 27;
    float4 mn = make_float4(INFINITY, INFINITY, INFINITY, INFINITY);
    float4 mx = make_float4(-INFINITY, -INFINITY, -INFINITY, -INFINITY);
    #pragma unroll 9
    for (int k = 0; k < 27; k++) {
        int row = pm[k];
        float4 v = *reinterpret_cast<const float4*>(draw + (size_t)row * C + c4 * 4);
        mn.x = fminf(mn.x, v.x); mn.y = fminf(mn.y, v.y);
        mn.z = fminf(mn.z, v.z); mn.w = fminf(mn.w, v.w);
        mx.x = fmaxf(mx.x, v.x); mx.y = fmaxf(mx.y, v.y);
        mx.z = fmaxf(mx.z, v.z); mx.w = fmaxf(mx.w, v.w);
    }
    float4 o;
    o.x = nlr(sc[0] >= 0.f ? mx.x : mn.x, sc[0], sh[0]);
    o.y = nlr(sc[1] >= 0.f ? mx.y : mn.y, sc[1], sh[1]);
    o.z = nlr(sc[2] >= 0.f ? mx.z : mn.z, sc[2], sh[2]);
    o.w = nlr(sc[3] >= 0.f ? mx.w : mn.w, sc[3], sh[3]);
    *reinterpret_cast<float4*>(yout + (size_t)n * C + c4 * 4) = o;
}

// segment pooling over conv6 raw
__global__ void segpool2_kernel(const float* __restrict__ y,
                                const float* __restrict__ sums,
                                const float* __restrict__ g, const float* __restrict__ b,
                                float inv_n, float* __restrict__ z) {
    int bi = blockIdx.x;
    int c = threadIdx.x;  // 512
    float sc, sh;
    bn_coef(sums, g, b, 512, c, inv_n, sc, sh);
    float mn = INFINITY, mx = -INFINITY, sm = 0.f;
    for (int r = 0; r < 32; r++) {
        float v = y[(size_t)(bi * 32 + r) * 512 + c];
        mn = fminf(mn, v);
        mx = fmaxf(mx, v);
        sm += nlr(v, sc, sh);
    }
    z[bi * 1024 + c] = nlr(sc >= 0.f ? mx : mn, sc, sh);
    z[bi * 1024 + 512 + c] = sm * (1.f / 32.f);
}

// FC (M=8): grid (COUT/64, KSPLIT); optional input normalization at staging
template <int K, int COUT, int KSPLIT, bool NORM>
__global__ __launch_bounds__(256) void fc_kernel(
    const float* __restrict__ z, const float* __restrict__ w,
    const float* __restrict__ ns, const float* __restrict__ ng,
    const float* __restrict__ nb, float inv_n,
    float* __restrict__ out) {
    constexpr int KC = K / KSPLIT;
    constexpr int KG = KC / 16;
    __shared__ __align__(16) float zt[KC * 8];
    __shared__ float red[16 * 520];

    const int cobase = blockIdx.x * 64;
    const int kc0 = blockIdx.y * KC;
    const int tid = threadIdx.x;
    const int coq = tid & 15;
    const int kg = tid >> 4;

    for (int idx = tid; idx < 8 * (KC / 4); idx += 256) {
        int n = idx / (KC / 4);
        int kq = idx - n * (KC / 4);
        float4 v = *reinterpret_cast<const float4*>(z + (size_t)n * K + kc0 + kq * 4);
        if constexpr (NORM) {
            #pragma unroll
            for (int j = 0; j < 4; j++) {
                float sc, sh;
                bn_coef(ns, ng, nb, K, kc0 + kq * 4 + j, inv_n, sc, sh);
                float* pv = j == 0 ? &v.x : j == 1 ? &v.y : j == 2 ? &v.z : &v.w;
                *pv = nlr(*pv, sc, sh);
            }
        }
        zt[(kq * 4 + 0) * 8 + n] = v.x;
        zt[(kq * 4 + 1) * 8 + n] = v.y;
        zt[(kq * 4 + 2) * 8 + n] = v.z;
        zt[(kq * 4 + 3) * 8 + n] = v.w;
    }
    __syncthreads();

    float4 acc[8];
    #pragma unroll
    for (int n = 0; n < 8; n++) acc[n] = make_float4(0.f, 0.f, 0.f, 0.f);
    for (int ki = 0; ki < KG; ki++) {
        int k = kg * KG + ki;
        float4 wv = *reinterpret_cast<const float4*>(
            w + (size_t)(kc0 + k) * COUT + cobase + coq * 4);
        float4 za = *reinterpret_cast<const float4*>(&zt[k * 8]);
        float4 zb = *reinterpret_cast<const float4*>(&zt[k * 8 + 4]);
        fma4(za.x, wv, acc[0]); fma4(za.y, wv, acc[1]);
        fma4(za.z, wv, acc[2]); fma4(za.w, wv, acc[3]);
        fma4(zb.x, wv, acc[4]); fma4(zb.y, wv, acc[5]);
        fma4(zb.z, wv, acc[6]); fma4(zb.w, wv, acc[7]);
    }
    #pragma unroll
    for (int n = 0; n < 8; n++) {
        red[kg * 520 + (coq * 4 + 0) * 8 + n] = acc[n].x;
        red[kg * 520 + (coq * 4 + 1) * 8 + n] = acc[n].y;
        red[kg * 520 + (coq * 4 + 2) * 8 + n] = acc[n].z;
        red[kg * 520 + (coq * 4 + 3) * 8 + n] = acc[n].w;
    }
    __syncthreads();
    for (int oi = tid; oi < 512; oi += 256) {
        int c = oi >> 3;
        int n = oi & 7;
        float s = 0.f;
        #pragma unroll
        for (int gg = 0; gg < 16; gg++) s += red[gg * 520 + c * 8 + n];
        float* op = out + (size_t)n * COUT + cobase + c;
        if (KSPLIT > 1) atomicAdd(op, s);
        else *op = s;
    }
}

// f3: normalize f2 raw into LDS, then [8,256]@[256,20]+bias
__global__ void f3n_kernel(const float* __restrict__ in, const float* __restrict__ w,
                           const float* __restrict__ bias,
                           const float* __restrict__ sums, const float* __restrict__ g,
                           const float* __restrict__ b, float inv_n,
                           float* __restrict__ out) {
    __shared__ float zin[8 * 256];
    int tid = threadIdx.x;  // 256
    for (int idx = tid; idx < 2048; idx += 256) {
        int c = idx & 255;
        float sc, sh;
        bn_coef(sums, g, b, 256, c, inv_n, sc, sh);
        zin[idx] = nlr(in[idx], sc, sh);
    }
    __syncthreads();
    if (tid >= 160) return;
    int n = tid / 20, co = tid % 20;
    float acc = bias[co];
    for (int ci = 0; ci < 256; ci++)
        acc = fmaf(zin[n * 256 + ci], w[ci * 20 + co], acc);
    out[tid] = acc;
}

// ---------------------------------------------------------------------------

extern "C" void kernel_launch(void* const* d_in, const int* in_sizes, int n_in,
                              void* d_out, int out_size, void* d_ws, size_t ws_size,
                              hipStream_t stream) {
    (void)in_sizes; (void)n_in; (void)out_size; (void)ws_size;

    const int N0 = 131072, N1 = 32768, N2 = 8192, N3 = 2048, N4 = 512, N5 = 256;

    const float* x      = (const float*)d_in[0];
    const float* w_mlp1 = (const float*)d_in[1];
    const float* g_mlp1 = (const float*)d_in[2];
    const float* b_mlp1 = (const float*)d_in[3];
    const float* w_c[6]; const float* g_c[6]; const float* b_c[6];
    for (int i = 0; i < 6; i++) {
        w_c[i] = (const float*)d_in[4 + 3 * i];
        g_c[i] = (const float*)d_in[5 + 3 * i];
        b_c[i] = (const float*)d_in[6 + 3 * i];
    }
    const float* w_d[5]; const float* g_d[5]; const float* b_d[5];
    for (int i = 0; i < 5; i++) {
        w_d[i] = (const float*)d_in[22 + 3 * i];
        g_d[i] = (const float*)d_in[23 + 3 * i];
        b_d[i] = (const float*)d_in[24 + 3 * i];
    }
    const float* w_f1 = (const float*)d_in[37];
    const float* g_f1 = (const float*)d_in[38];
    const float* b_f1 = (const float*)d_in[39];
    const float* w_f2 = (const float*)d_in[40];
    const float* g_f2 = (const float*)d_in[41];
    const float* b_f2 = (const float*)d_in[42];
    const float* w_f3 = (const float*)d_in[43];
    const float* bias_f3 = (const float*)d_in[44];
    const int* nbr[6];
    for (int i = 0; i < 6; i++) nbr[i] = (const int*)d_in[45 + i];
    const int* pool[5];
    for (int i = 0; i < 5; i++) pool[i] = (const int*)d_in[51 + i];

    float* ws    = (float*)d_ws;
    float* bufA  = ws;                    // y buffers / fc outs
    float* bufB  = bufA + 2097152;        // conv finals / fc2 out
    float* bufC  = bufB + 4194304;        // down raw / conv partials / z
    float* stats = bufC + 4194304;        // 14 * 1024
    float* out = (float*)d_out;

    auto st = [&](int slot) { return stats + slot * 1024; };
    auto run_stats = [&](const float* buf, int total, int C, int bs, int slot) {
        int total4 = total / 4, C4 = C / 4;
        int gr = (total4 + bs - 1) / bs;
        if (gr > 768) gr = 768;
        stats4_kernel<<<gr, bs, 0, stream>>>((const float4*)buf, total4, C, C4, st(slot));
    };

    const float iN0 = 1.f / N0, iN1 = 1.f / N1, iN2 = 1.f / N2, iN3 = 1.f / N3,
                iN4 = 1.f / N4, iN5 = 1.f / N5, i8 = 1.f / 8.f;

    zero_kernel<<<56, 256, 0, stream>>>(stats, 14 * 1024);

    // ---- mlp1 raw -> bufA; stats slot 0
    mlp1_kernel<<<N0 / 256, 256, 0, stream>>>(x, w_mlp1, bufA, N0);
    run_stats(bufA, N0 * 16, 16, 256, 0);

    // ---- level 0: conv1 16->32 (norm in, fused stats slot1)
    convd_kernel<16, 32, 32, 1, 1024, 128, 256, 2, 27, true, true>
        <<<1024, 256, 0, stream>>>(bufA, nbr[0], w_c[0], bufB,
                                   st(0), g_mlp1, b_mlp1, iN0, st(1));
    down3_kernel<16, 32, 32, 2, 256, true>
        <<<1024, 256, 0, stream>>>(bufA, bufB, w_d[0], bufC,
                                   st(0), g_mlp1, b_mlp1, iN0,
                                   st(1), g_c[0], b_c[0], iN0, st(2));
    pool2_kernel<32, 256><<<N1 * 8 / 256, 256, 0, stream>>>(
        bufC, pool[0], st(2), g_d[0], b_d[0], iN0, bufA, N1);

    // ---- level 1: conv2 32->48
    convd_kernel<32, 48, 48, 1, 512, 64, 192, 2, 27, false, true>
        <<<512, 192, 0, stream>>>(bufA, nbr[1], w_c[1], bufB,
                                  nullptr, nullptr, nullptr, 0.f, st(3));
    down3_kernel<32, 48, 48, 2, 192, false>
        <<<512, 192, 0, stream>>>(bufA, bufB, w_d[1], bufC,
                                  nullptr, nullptr, nullptr, 0.f,
                                  st(3), g_c[1], b_c[1], iN1, st(4));
    pool2_kernel<48, 192><<<N2 * 12 / 192, 192, 0, stream>>>(
        bufC, pool[1], st(4), g_d[1], b_d[1], iN1, bufA, N2);

    // ---- level 2: conv3 48->96 (2 co-tiles)
    convd_kernel<48, 96, 48, 2, 128, 64, 192, 2, 27, false, true>
        <<<256, 192, 0, stream>>>(bufA, nbr[2], w_c[2], bufB,
                                  nullptr, nullptr, nullptr, 0.f, st(5));
    down3_kernel<48, 96, 96, 2, 192, false>
        <<<256, 192, 0, stream>>>(bufA, bufB, w_d[2], bufC,
                                  nullptr, nullptr, nullptr, 0.f,
                                  st(5), g_c[2], b_c[2], iN2, st(6));
    pool2_kernel<96, 192><<<N3 * 24 / 192, 192, 0, stream>>>(
        bufC, pool[2], st(6), g_d[2], b_d[2], iN2, bufA, N3);

    // ---- level 3: conv4 96->128, k-split 9 partials -> bufC, reduce -> bufB
    convd_kernel<96, 128, 64, 2, 32, 64, 256, 2, 3, false, false>
        <<<576, 256, 0, stream>>>(bufA, nbr[3], w_c[3], bufC,
                                  nullptr, nullptr, nullptr, 0.f, nullptr);
    reducek_kernel<128, 9><<<256, 256, 0, stream>>>(
        (const float4*)bufC, (float4*)bufB, N3 * 32, st(7));
    down3_kernel<96, 128, 128, 2, 256, false>
        <<<64, 256, 0, stream>>>(bufA, bufB, w_d[3], bufC,
                                 nullptr, nullptr, nullptr, 0.f,
                                 st(7), g_c[3], b_c[3], iN3, st(8));
    pool2_kernel<128, 256><<<N4 * 32 / 256, 256, 0, stream>>>(
        bufC, pool[3], st(8), g_d[3], b_d[3], iN3, bufA, N4);

    // ---- level 4: conv5 128->256, k-split 9
    convd_kernel<128, 256, 64, 4, 8, 64, 256, 2, 3, false, false>
        <<<288, 256, 0, stream>>>(bufA, nbr[4], w_c[4], bufC,
                                  nullptr, nullptr, nullptr, 0.f, nullptr);
    reducek_kernel<256, 9><<<128, 256, 0, stream>>>(
        (const float4*)bufC, (float4*)bufB, N4 * 64, st(9));
    down3_kernel<128, 256, 256, 2, 256, false>
        <<<32, 256, 0, stream>>>(bufA, bufB, w_d[4], bufC,
                                 nullptr, nullptr, nullptr, 0.f,
                                 st(9), g_c[4], b_c[4], iN4, st(10));
    pool2_kernel<256, 256><<<N5 * 64 / 256, 256, 0, stream>>>(
        bufC, pool[4], st(10), g_d[4], b_d[4], iN4, bufA, N5);

    // ---- conv6 256->512, k-split 27 (XCD co-slices)
    convd_kernel<256, 512, 64, 8, 4, 64, 256, 2, 1, false, false>
        <<<864, 256, 0, stream>>>(bufA, nbr[5], w_c[5], bufC,
                                  nullptr, nullptr, nullptr, 0.f, nullptr);
    reducek_kernel<512, 27><<<128, 256, 0, stream>>>(
        (const float4*)bufC, (float4*)bufB, N5 * 128, st(11));

    // ---- segment pooling (applies conv6 BN) -> z in bufC
    segpool2_kernel<<<8, 512, 0, stream>>>(bufB, st(11), g_c[5], b_c[5], iN5, bufC);

    // ---- f1: z @ w_f1 raw -> bufA
    zero_kernel<<<16, 256, 0, stream>>>(bufA, 4096);
    fc_kernel<1024, 512, 4, false><<<dim3(8, 4), 256, 0, stream>>>(
        bufC, w_f1, nullptr, nullptr, nullptr, 0.f, bufA);
    run_stats(bufA, 8 * 512, 512, 256, 12);

    // ---- f2: normalize(f1) @ w_f2 raw -> bufB
    zero_kernel<<<8, 256, 0, stream>>>(bufB, 2048);
    fc_kernel<512, 256, 4, true><<<dim3(4, 4), 256, 0, stream>>>(
        bufA, w_f2, st(12), g_f1, b_f1, i8, bufB);
    run_stats(bufB, 8 * 256, 256, 256, 13);

    // ---- f3
    f3n_kernel<<<1, 256, 0, stream>>>(bufB, w_f3, bias_f3, st(13), g_f2, b_f2, i8, out);
}

// Round 5
// 1054.746 us; speedup vs baseline: 1.1229x; 1.0889x over previous
//
#include <hip/hip_runtime.h>
#include <math.h>

#define BN_EPS 1e-5f

// ---------------------------------------------------------------------------
// Round 5: deep k-split convs (partial arena + fused reduce/stats) for
// occupancy; register double-buffered k-lookahead gathers for conv1.
// BN fused into consumers throughout (min/max pool trick, etc).
// ---------------------------------------------------------------------------

__device__ __forceinline__ void fma4(float s, const float4& w, float4& a) {
    a.x = fmaf(s, w.x, a.x);
    a.y = fmaf(s, w.y, a.y);
    a.z = fmaf(s, w.z, a.z);
    a.w = fmaf(s, w.w, a.w);
}

__device__ __forceinline__ float nlr(float x, float sc, float sh) {
    float t = fmaf(x, sc, sh);
    return fmaxf(t, 0.01f * t);
}

__device__ __forceinline__ void bn_coef(const float* __restrict__ sums,
                                        const float* __restrict__ g,
                                        const float* __restrict__ b,
                                        int C, int c, float inv_n,
                                        float& sc, float& sh) {
    float mean = sums[c] * inv_n;
    float var = fmaxf(fmaf(-mean, mean, sums[C + c] * inv_n), 0.f);
    sc = g[c] * rsqrtf(var + BN_EPS);
    sh = fmaf(-mean, sc, b[c]);
}

__global__ void zero_kernel(float* __restrict__ p, int n) {
    int i = blockIdx.x * blockDim.x + threadIdx.x;
    if (i < n) p[i] = 0.f;
}

__global__ void mlp1_kernel(const float* __restrict__ x, const float* __restrict__ w,
                            float* __restrict__ out, int N) {
    int n = blockIdx.x * blockDim.x + threadIdx.x;
    if (n >= N) return;
    float x0 = x[n * 3], x1 = x[n * 3 + 1], x2 = x[n * 3 + 2];
    #pragma unroll
    for (int c4 = 0; c4 < 4; c4++) {
        float4 w0 = *reinterpret_cast<const float4*>(w + 0 + c4 * 4);
        float4 w1 = *reinterpret_cast<const float4*>(w + 16 + c4 * 4);
        float4 w2 = *reinterpret_cast<const float4*>(w + 32 + c4 * 4);
        float4 o;
        o.x = fmaf(x0, w0.x, fmaf(x1, w1.x, x2 * w2.x));
        o.y = fmaf(x0, w0.y, fmaf(x1, w1.y, x2 * w2.y));
        o.z = fmaf(x0, w0.z, fmaf(x1, w1.z, x2 * w2.z));
        o.w = fmaf(x0, w0.w, fmaf(x1, w1.w, x2 * w2.w));
        *reinterpret_cast<float4*>(out + n * 16 + c4 * 4) = o;
    }
}

// per-channel sum & sumsq, float4; requires blockDim % C4 == 0
__global__ void stats4_kernel(const float4* __restrict__ x, int total4, int C, int C4,
                              float* __restrict__ sums) {
    __shared__ float ls[1024];
    int tid = threadIdx.x;
    for (int j = tid; j < 2 * C; j += blockDim.x) ls[j] = 0.f;
    __syncthreads();
    int stride = gridDim.x * blockDim.x;
    int i = blockIdx.x * blockDim.x + tid;
    int c4 = i % C4;
    float4 s = make_float4(0.f, 0.f, 0.f, 0.f);
    float4 q = make_float4(0.f, 0.f, 0.f, 0.f);
    for (; i < total4; i += stride) {
        float4 v = x[i];
        s.x += v.x; s.y += v.y; s.z += v.z; s.w += v.w;
        q.x = fmaf(v.x, v.x, q.x); q.y = fmaf(v.y, v.y, q.y);
        q.z = fmaf(v.z, v.z, q.z); q.w = fmaf(v.w, v.w, q.w);
    }
    int cb = c4 * 4;
    atomicAdd(&ls[cb + 0], s.x); atomicAdd(&ls[cb + 1], s.y);
    atomicAdd(&ls[cb + 2], s.z); atomicAdd(&ls[cb + 3], s.w);
    atomicAdd(&ls[C + cb + 0], q.x); atomicAdd(&ls[C + cb + 1], q.y);
    atomicAdd(&ls[C + cb + 2], q.z); atomicAdd(&ls[C + cb + 3], q.w);
    __syncthreads();
    for (int j = tid; j < 2 * C; j += blockDim.x) atomicAdd(&sums[j], ls[j]);
}

// reduce KS k-split partial slices + write final (aliases slice 0, element-wise
// safe) + fused stats.  Requires blockDim % (C/4) == 0.
template <int C, int KS>
__global__ void reducek_kernel(const float4* __restrict__ in, float4* __restrict__ out,
                               int total4, float* __restrict__ sums) {
    __shared__ float ls[1024];
    constexpr int C4 = C / 4;
    int tid = threadIdx.x;
    for (int j = tid; j < 2 * C; j += blockDim.x) ls[j] = 0.f;
    __syncthreads();
    int stride = gridDim.x * blockDim.x;
    int i = blockIdx.x * blockDim.x + tid;
    int c4 = i % C4;
    float4 s = make_float4(0.f, 0.f, 0.f, 0.f);
    float4 q = make_float4(0.f, 0.f, 0.f, 0.f);
    for (; i < total4; i += stride) {
        float4 v = make_float4(0.f, 0.f, 0.f, 0.f);
        #pragma unroll
        for (int p = 0; p < KS; p++) {
            float4 t = in[(size_t)p * total4 + i];
            v.x += t.x; v.y += t.y; v.z += t.z; v.w += t.w;
        }
        out[i] = v;
        s.x += v.x; s.y += v.y; s.z += v.z; s.w += v.w;
        q.x = fmaf(v.x, v.x, q.x); q.y = fmaf(v.y, v.y, q.y);
        q.z = fmaf(v.z, v.z, q.z); q.w = fmaf(v.w, v.w, q.w);
    }
    int cb = c4 * 4;
    atomicAdd(&ls[cb + 0], s.x); atomicAdd(&ls[cb + 1], s.y);
    atomicAdd(&ls[cb + 2], s.z); atomicAdd(&ls[cb + 3], s.w);
    atomicAdd(&ls[C + cb + 0], q.x); atomicAdd(&ls[C + cb + 1], q.y);
    atomicAdd(&ls[C + cb + 2], q.z); atomicAdd(&ls[C + cb + 3], q.w);
    __syncthreads();
    for (int j = tid; j < 2 * C; j += blockDim.x) atomicAdd(&sums[j], ls[j]);
}

// ---------------------------------------------------------------------------
// Direct sparse conv.  1-D grid = NCOT * MT * KS; bid -> (cot, mt, ks).
// Each thread: RT rows x NQ co-quads.  PREF: register double-buffered y
// lookahead (one k ahead, named A/B buffers).  k-split writes partial slices
// at out + ks*N*COUT.
// ---------------------------------------------------------------------------
template <int CIN, int COUT, int CO_TILE, int NCOT, int MT, int TM, int NTHR,
          int NQ, int KT, bool NORM_IN, bool STATS, bool PREF>
__global__ __launch_bounds__(NTHR) void convd_kernel(
    const float* __restrict__ y, const int* __restrict__ nbr,
    const float* __restrict__ w, float* __restrict__ out,
    const float* __restrict__ s_in, const float* __restrict__ g_in,
    const float* __restrict__ b_in, float inv_n,
    float* __restrict__ s_out) {
    constexpr int CQT = CO_TILE / (4 * NQ);
    constexpr int MGRP = NTHR / CQT;
    constexpr int RT = TM / MGRP;
    constexpr int C4N = CIN / 4;
    static_assert(MGRP * RT == TM, "tile mismatch");
    static_assert(MGRP * CQT == NTHR, "thread mismatch");

    __shared__ float nsc[NORM_IN ? CIN : 1];
    __shared__ float nsh[NORM_IN ? CIN : 1];
    __shared__ float sred[STATS ? 2 * CO_TILE : 1];

    const int tid = threadIdx.x;
    const int bid = blockIdx.x;
    const int cot = bid % NCOT;
    const int rest = bid / NCOT;
    const int mt = rest % MT;
    const int ks = rest / MT;
    const int m0 = mt * TM;
    const int cobase = cot * CO_TILE;
    const int k0 = ks * KT;
    const int cq = tid % CQT;
    const int mg = tid / CQT;

    if constexpr (NORM_IN) {
        for (int c = tid; c < CIN; c += NTHR) {
            float sc, sh;
            bn_coef(s_in, g_in, b_in, CIN, c, inv_n, sc, sh);
            nsc[c] = sc;
            nsh[c] = sh;
        }
    }

    int mrow[RT];
    #pragma unroll
    for (int r = 0; r < RT; r++) mrow[r] = m0 + mg + r * MGRP;

    float4 acc[RT][NQ];
    #pragma unroll
    for (int r = 0; r < RT; r++)
        #pragma unroll
        for (int q = 0; q < NQ; q++) acc[r][q] = make_float4(0.f, 0.f, 0.f, 0.f);

    auto ldidx = [&](int k, int (&rr)[RT]) {
        #pragma unroll
        for (int r = 0; r < RT; r++) rr[r] = nbr[(size_t)mrow[r] * 27 + k];
    };
    auto fma_ci4 = [&](const float* wk, int ci4, float4 (&yv)[RT]) {
        if constexpr (NORM_IN) {
            float4 sc = *reinterpret_cast<const float4*>(&nsc[ci4 * 4]);
            float4 sh = *reinterpret_cast<const float4*>(&nsh[ci4 * 4]);
            #pragma unroll
            for (int r = 0; r < RT; r++) {
                yv[r].x = nlr(yv[r].x, sc.x, sh.x);
                yv[r].y = nlr(yv[r].y, sc.y, sh.y);
                yv[r].z = nlr(yv[r].z, sc.z, sh.z);
                yv[r].w = nlr(yv[r].w, sc.w, sh.w);
            }
        }
        #pragma unroll
        for (int jj = 0; jj < 4; jj++) {
            #pragma unroll
            for (int q = 0; q < NQ; q++) {
                float4 wv = *reinterpret_cast<const float4*>(
                    wk + (size_t)(ci4 * 4 + jj) * COUT + q * 4);
                #pragma unroll
                for (int r = 0; r < RT; r++) {
                    float e = jj == 0 ? yv[r].x : jj == 1 ? yv[r].y
                             : jj == 2 ? yv[r].z : yv[r].w;
                    fma4(e, wv, acc[r][q]);
                }
            }
        }
    };

    if constexpr (PREF) {
        auto ldy = [&](const int (&rr)[RT], float4 (&yv)[RT][C4N]) {
            #pragma unroll
            for (int r = 0; r < RT; r++)
                #pragma unroll
                for (int c4 = 0; c4 < C4N; c4++)
                    yv[r][c4] = *reinterpret_cast<const float4*>(
                        y + (size_t)rr[r] * CIN + c4 * 4);
        };
        auto fmak = [&](int k, float4 (&yv)[RT][C4N]) {
            const float* wk = w + (size_t)k * CIN * COUT + cobase + cq * (4 * NQ);
            #pragma unroll
            for (int ci4 = 0; ci4 < C4N; ci4++) {
                float4 col[RT];
                #pragma unroll
                for (int r = 0; r < RT; r++) col[r] = yv[r][ci4];
                fma_ci4(wk, ci4, col);
            }
        };
        int ra[RT], rb[RT];
        float4 ya[RT][C4N], yb[RT][C4N];
        ldidx(k0, ra);
        ldy(ra, ya);
        if constexpr (NORM_IN) __syncthreads();
        int kk = 0;
        for (; kk + 2 <= KT; kk += 2) {
            ldidx(k0 + kk + 1, rb);
            ldy(rb, yb);
            fmak(k0 + kk, ya);
            if (kk + 2 < KT) {
                ldidx(k0 + kk + 2, ra);
                ldy(ra, ya);
            }
            fmak(k0 + kk + 1, yb);
        }
        if (KT & 1) fmak(k0 + KT - 1, ya);
    } else {
        if constexpr (NORM_IN) __syncthreads();
        int rows[RT];
        ldidx(k0, rows);
        for (int kk = k0; kk < k0 + KT; kk++) {
            int rnext[RT];
            if (kk + 1 < k0 + KT) ldidx(kk + 1, rnext);
            const float* wk = w + (size_t)kk * CIN * COUT + cobase + cq * (4 * NQ);
            #pragma unroll 4
            for (int ci4 = 0; ci4 < C4N; ci4++) {
                float4 yv[RT];
                #pragma unroll
                for (int r = 0; r < RT; r++)
                    yv[r] = *reinterpret_cast<const float4*>(
                        y + (size_t)rows[r] * CIN + ci4 * 4);
                fma_ci4(wk, ci4, yv);
            }
            #pragma unroll
            for (int r = 0; r < RT; r++) rows[r] = rnext[r];
        }
    }

    float* outp = out + (size_t)ks * MT * TM * COUT;
    #pragma unroll
    for (int r = 0; r < RT; r++)
        #pragma unroll
        for (int q = 0; q < NQ; q++)
            *reinterpret_cast<float4*>(
                outp + (size_t)mrow[r] * COUT + cobase + cq * (4 * NQ) + q * 4) =
                acc[r][q];

    if constexpr (STATS) {
        for (int j = tid; j < 2 * CO_TILE; j += NTHR) sred[j] = 0.f;
        __syncthreads();
        #pragma unroll
        for (int q = 0; q < NQ; q++) {
            float4 s = make_float4(0.f, 0.f, 0.f, 0.f);
            float4 qq = make_float4(0.f, 0.f, 0.f, 0.f);
            #pragma unroll
            for (int r = 0; r < RT; r++) {
                float4 v = acc[r][q];
                s.x += v.x; s.y += v.y; s.z += v.z; s.w += v.w;
                qq.x = fmaf(v.x, v.x, qq.x); qq.y = fmaf(v.y, v.y, qq.y);
                qq.z = fmaf(v.z, v.z, qq.z); qq.w = fmaf(v.w, v.w, qq.w);
            }
            int cb = cq * (4 * NQ) + q * 4;
            atomicAdd(&sred[cb + 0], s.x); atomicAdd(&sred[cb + 1], s.y);
            atomicAdd(&sred[cb + 2], s.z); atomicAdd(&sred[cb + 3], s.w);
            atomicAdd(&sred[CO_TILE + cb + 0], qq.x);
            atomicAdd(&sred[CO_TILE + cb + 1], qq.y);
            atomicAdd(&sred[CO_TILE + cb + 2], qq.z);
            atomicAdd(&sred[CO_TILE + cb + 3], qq.w);
        }
        __syncthreads();
        for (int j = tid; j < CO_TILE; j += NTHR) {
            atomicAdd(&s_out[cobase + j], sred[j]);
            atomicAdd(&s_out[COUT + cobase + j], sred[CO_TILE + j]);
        }
    }
}

// ---------------------------------------------------------------------------
// down (concat + 1x1) with fused stats; inputs normalized on the fly.
// ---------------------------------------------------------------------------
template <int C1, int C2, int COUT, int NQ, int NTHR, bool NORM1>
__global__ __launch_bounds__(NTHR) void down3_kernel(
    const float* __restrict__ in1, const float* __restrict__ in2,
    const float* __restrict__ w, float* __restrict__ out,
    const float* __restrict__ s1, const float* __restrict__ g1,
    const float* __restrict__ b1, float inv1,
    const float* __restrict__ s2, const float* __restrict__ g2,
    const float* __restrict__ b2, float inv2,
    float* __restrict__ s_out) {
    constexpr int CQT = COUT / (4 * NQ);
    constexpr int PAIRS = NTHR / CQT;
    __shared__ __align__(16) float n1c[C1], n1h[C1], n2c[C2], n2h[C2];
    __shared__ float sred[2 * COUT];

    const int tid = threadIdx.x;
    if constexpr (NORM1) {
        for (int c = tid; c < C1; c += NTHR) {
            float sc, sh;
            bn_coef(s1, g1, b1, C1, c, inv1, sc, sh);
            n1c[c] = sc; n1h[c] = sh;
        }
    }
    for (int c = tid; c < C2; c += NTHR) {
        float sc, sh;
        bn_coef(s2, g2, b2, C2, c, inv2, sc, sh);
        n2c[c] = sc; n2h[c] = sh;
    }
    for (int j = tid; j < 2 * COUT; j += NTHR) sred[j] = 0.f;
    __syncthreads();

    const int cq = tid % CQT;
    const int pr = tid / CQT;
    const int n0 = (blockIdx.x * PAIRS + pr) * 2;

    float4 acc[2][NQ];
    #pragma unroll
    for (int r = 0; r < 2; r++)
        #pragma unroll
        for (int q = 0; q < NQ; q++) acc[r][q] = make_float4(0.f, 0.f, 0.f, 0.f);

    const float* w1 = w + cq * (4 * NQ);
    #pragma unroll 8
    for (int ci4 = 0; ci4 < C1 / 4; ci4++) {
        float4 a0 = *reinterpret_cast<const float4*>(in1 + (size_t)n0 * C1 + ci4 * 4);
        float4 a1 = *reinterpret_cast<const float4*>(in1 + (size_t)(n0 + 1) * C1 + ci4 * 4);
        if constexpr (NORM1) {
            float4 sc = *reinterpret_cast<const float4*>(&n1c[ci4 * 4]);
            float4 sh = *reinterpret_cast<const float4*>(&n1h[ci4 * 4]);
            a0.x = nlr(a0.x, sc.x, sh.x); a0.y = nlr(a0.y, sc.y, sh.y);
            a0.z = nlr(a0.z, sc.z, sh.z); a0.w = nlr(a0.w, sc.w, sh.w);
            a1.x = nlr(a1.x, sc.x, sh.x); a1.y = nlr(a1.y, sc.y, sh.y);
            a1.z = nlr(a1.z, sc.z, sh.z); a1.w = nlr(a1.w, sc.w, sh.w);
        }
        #pragma unroll
        for (int jj = 0; jj < 4; jj++) {
            const float* wp = w1 + (size_t)(ci4 * 4 + jj) * COUT;
            float e0 = jj == 0 ? a0.x : jj == 1 ? a0.y : jj == 2 ? a0.z : a0.w;
            float e1 = jj == 0 ? a1.x : jj == 1 ? a1.y : jj == 2 ? a1.z : a1.w;
            #pragma unroll
            for (int q = 0; q < NQ; q++) {
                float4 wv = *reinterpret_cast<const float4*>(wp + q * 4);
                fma4(e0, wv, acc[0][q]);
                fma4(e1, wv, acc[1][q]);
            }
        }
    }
    const float* w2 = w + (size_t)C1 * COUT + cq * (4 * NQ);
    #pragma unroll 8
    for (int ci4 = 0; ci4 < C2 / 4; ci4++) {
        float4 a0 = *reinterpret_cast<const float4*>(in2 + (size_t)n0 * C2 + ci4 * 4);
        float4 a1 = *reinterpret_cast<const float4*>(in2 + (size_t)(n0 + 1) * C2 + ci4 * 4);
        float4 sc = *reinterpret_cast<const float4*>(&n2c[ci4 * 4]);
        float4 sh = *reinterpret_cast<const float4*>(&n2h[ci4 * 4]);
        a0.x = nlr(a0.x, sc.x, sh.x); a0.y = nlr(a0.y, sc.y, sh.y);
        a0.z = nlr(a0.z, sc.z, sh.z); a0.w = nlr(a0.w, sc.w, sh.w);
        a1.x = nlr(a1.x, sc.x, sh.x); a1.y = nlr(a1.y, sc.y, sh.y);
        a1.z = nlr(a1.z, sc.z, sh.z); a1.w = nlr(a1.w, sc.w, sh.w);
        #pragma unroll
        for (int jj = 0; jj < 4; jj++) {
            const float* wp = w2 + (size_t)(ci4 * 4 + jj) * COUT;
            float e0 = jj == 0 ? a0.x : jj == 1 ? a0.y : jj == 2 ? a0.z : a0.w;
            float e1 = jj == 0 ? a1.x : jj == 1 ? a1.y : jj == 2 ? a1.z : a1.w;
            #pragma unroll
            for (int q = 0; q < NQ; q++) {
                float4 wv = *reinterpret_cast<const float4*>(wp + q * 4);
                fma4(e0, wv, acc[0][q]);
                fma4(e1, wv, acc[1][q]);
            }
        }
    }
    #pragma unroll
    for (int r = 0; r < 2; r++)
        #pragma unroll
        for (int q = 0; q < NQ; q++)
            *reinterpret_cast<float4*>(out + (size_t)(n0 + r) * COUT + cq * (4 * NQ) + q * 4) =
                acc[r][q];

    #pragma unroll
    for (int q = 0; q < NQ; q++) {
        float4 s = make_float4(0.f, 0.f, 0.f, 0.f);
        float4 qq = make_float4(0.f, 0.f, 0.f, 0.f);
        #pragma unroll
        for (int r = 0; r < 2; r++) {
            float4 v = acc[r][q];
            s.x += v.x; s.y += v.y; s.z += v.z; s.w += v.w;
            qq.x = fmaf(v.x, v.x, qq.x); qq.y = fmaf(v.y, v.y, qq.y);
            qq.z = fmaf(v.z, v.z, qq.z); qq.w = fmaf(v.w, v.w, qq.w);
        }
        int cb = cq * (4 * NQ) + q * 4;
        atomicAdd(&sred[cb + 0], s.x); atomicAdd(&sred[cb + 1], s.y);
        atomicAdd(&sred[cb + 2], s.z); atomicAdd(&sred[cb + 3], s.w);
        atomicAdd(&sred[COUT + cb + 0], qq.x);
        atomicAdd(&sred[COUT + cb + 1], qq.y);
        atomicAdd(&sred[COUT + cb + 2], qq.z);
        atomicAdd(&sred[COUT + cb + 3], qq.w);
    }
    __syncthreads();
    for (int j = tid; j < COUT; j += NTHR) {
        atomicAdd(&s_out[j], sred[j]);
        atomicAdd(&s_out[COUT + j], sred[COUT + j]);
    }
}

// ---------------------------------------------------------------------------
// pool: gather raw down output, min/max over 27, then BN+lrelu by scale sign
// ---------------------------------------------------------------------------
template <int C, int NTHR>
__global__ __launch_bounds__(NTHR) void pool2_kernel(
    const float* __restrict__ draw, const int* __restrict__ pmap,
    const float* __restrict__ sums, const float* __restrict__ g,
    const float* __restrict__ b, float inv_n,
    float* __restrict__ yout, int Nout) {
    constexpr int C4 = C / 4;
    int i = blockIdx.x * NTHR + threadIdx.x;
    if (i >= Nout * C4) return;
    int n = i / C4, c4 = i % C4;
    float sc[4], sh[4];
    #pragma unroll
    for (int j = 0; j < 4; j++) bn_coef(sums, g, b, C, c4 * 4 + j, inv_n, sc[j], sh[j]);
    const int* pm = pmap + n * 27;
    float4 mn = make_float4(INFINITY, INFINITY, INFINITY, INFINITY);
    float4 mx = make_float4(-INFINITY, -INFINITY, -INFINITY, -INFINITY);
    #pragma unroll 9
    for (int k = 0; k < 27; k++) {
        int row = pm[k];
        float4 v = *reinterpret_cast<const float4*>(draw + (size_t)row * C + c4 * 4);
        mn.x = fminf(mn.x, v.x); mn.y = fminf(mn.y, v.y);
        mn.z = fminf(mn.z, v.z); mn.w = fminf(mn.w, v.w);
        mx.x = fmaxf(mx.x, v.x); mx.y = fmaxf(mx.y, v.y);
        mx.z = fmaxf(mx.z, v.z); mx.w = fmaxf(mx.w, v.w);
    }
    float4 o;
    o.x = nlr(sc[0] >= 0.f ? mx.x : mn.x, sc[0], sh[0]);
    o.y = nlr(sc[1] >= 0.f ? mx.y : mn.y, sc[1], sh[1]);
    o.z = nlr(sc[2] >= 0.f ? mx.z : mn.z, sc[2], sh[2]);
    o.w = nlr(sc[3] >= 0.f ? mx.w : mn.w, sc[3], sh[3]);
    *reinterpret_cast<float4*>(yout + (size_t)n * C + c4 * 4) = o;
}

__global__ void segpool2_kernel(const float* __restrict__ y,
                                const float* __restrict__ sums,
                                const float* __restrict__ g, const float* __restrict__ b,
                                float inv_n, float* __restrict__ z) {
    int bi = blockIdx.x;
    int c = threadIdx.x;  // 512
    float sc, sh;
    bn_coef(sums, g, b, 512, c, inv_n, sc, sh);
    float mn = INFINITY, mx = -INFINITY, sm = 0.f;
    for (int r = 0; r < 32; r++) {
        float v = y[(size_t)(bi * 32 + r) * 512 + c];
        mn = fminf(mn, v);
        mx = fmaxf(mx, v);
        sm += nlr(v, sc, sh);
    }
    z[bi * 1024 + c] = nlr(sc >= 0.f ? mx : mn, sc, sh);
    z[bi * 1024 + 512 + c] = sm * (1.f / 32.f);
}

// FC (M=8): grid (COUT/64, KSPLIT); optional input normalization at staging
template <int K, int COUT, int KSPLIT, bool NORM>
__global__ __launch_bounds__(256) void fc_kernel(
    const float* __restrict__ z, const float* __restrict__ w,
    const float* __restrict__ ns, const float* __restrict__ ng,
    const float* __restrict__ nb, float inv_n,
    float* __restrict__ out) {
    constexpr int KC = K / KSPLIT;
    constexpr int KG = KC / 16;
    __shared__ __align__(16) float zt[KC * 8];
    __shared__ float red[16 * 520];

    const int cobase = blockIdx.x * 64;
    const int kc0 = blockIdx.y * KC;
    const int tid = threadIdx.x;
    const int coq = tid & 15;
    const int kg = tid >> 4;

    for (int idx = tid; idx < 8 * (KC / 4); idx += 256) {
        int n = idx / (KC / 4);
        int kq = idx - n * (KC / 4);
        float4 v = *reinterpret_cast<const float4*>(z + (size_t)n * K + kc0 + kq * 4);
        if constexpr (NORM) {
            #pragma unroll
            for (int j = 0; j < 4; j++) {
                float sc, sh;
                bn_coef(ns, ng, nb, K, kc0 + kq * 4 + j, inv_n, sc, sh);
                float* pv = j == 0 ? &v.x : j == 1 ? &v.y : j == 2 ? &v.z : &v.w;
                *pv = nlr(*pv, sc, sh);
            }
        }
        zt[(kq * 4 + 0) * 8 + n] = v.x;
        zt[(kq * 4 + 1) * 8 + n] = v.y;
        zt[(kq * 4 + 2) * 8 + n] = v.z;
        zt[(kq * 4 + 3) * 8 + n] = v.w;
    }
    __syncthreads();

    float4 acc[8];
    #pragma unroll
    for (int n = 0; n < 8; n++) acc[n] = make_float4(0.f, 0.f, 0.f, 0.f);
    for (int ki = 0; ki < KG; ki++) {
        int k = kg * KG + ki;
        float4 wv = *reinterpret_cast<const float4*>(
            w + (size_t)(kc0 + k) * COUT + cobase + coq * 4);
        float4 za = *reinterpret_cast<const float4*>(&zt[k * 8]);
        float4 zb = *reinterpret_cast<const float4*>(&zt[k * 8 + 4]);
        fma4(za.x, wv, acc[0]); fma4(za.y, wv, acc[1]);
        fma4(za.z, wv, acc[2]); fma4(za.w, wv, acc[3]);
        fma4(zb.x, wv, acc[4]); fma4(zb.y, wv, acc[5]);
        fma4(zb.z, wv, acc[6]); fma4(zb.w, wv, acc[7]);
    }
    #pragma unroll
    for (int n = 0; n < 8; n++) {
        red[kg * 520 + (coq * 4 + 0) * 8 + n] = acc[n].x;
        red[kg * 520 + (coq * 4 + 1) * 8 + n] = acc[n].y;
        red[kg * 520 + (coq * 4 + 2) * 8 + n] = acc[n].z;
        red[kg * 520 + (coq * 4 + 3) * 8 + n] = acc[n].w;
    }
    __syncthreads();
    for (int oi = tid; oi < 512; oi += 256) {
        int c = oi >> 3;
        int n = oi & 7;
        float s = 0.f;
        #pragma unroll
        for (int gg = 0; gg < 16; gg++) s += red[gg * 520 + c * 8 + n];
        float* op = out + (size_t)n * COUT + cobase + c;
        if (KSPLIT > 1) atomicAdd(op, s);
        else *op = s;
    }
}

__global__ void f3n_kernel(const float* __restrict__ in, const float* __restrict__ w,
                           const float* __restrict__ bias,
                           const float* __restrict__ sums, const float* __restrict__ g,
                           const float* __restrict__ b, float inv_n,
                           float* __restrict__ out) {
    __shared__ float zin[8 * 256];
    int tid = threadIdx.x;  // 256
    for (int idx = tid; idx < 2048; idx += 256) {
        int c = idx & 255;
        float sc, sh;
        bn_coef(sums, g, b, 256, c, inv_n, sc, sh);
        zin[idx] = nlr(in[idx], sc, sh);
    }
    __syncthreads();
    if (tid >= 160) return;
    int n = tid / 20, co = tid % 20;
    float acc = bias[co];
    for (int ci = 0; ci < 256; ci++)
        acc = fmaf(zin[n * 256 + ci], w[ci * 20 + co], acc);
    out[tid] = acc;
}

// ---------------------------------------------------------------------------

extern "C" void kernel_launch(void* const* d_in, const int* in_sizes, int n_in,
                              void* d_out, int out_size, void* d_ws, size_t ws_size,
                              hipStream_t stream) {
    (void)in_sizes; (void)n_in; (void)out_size; (void)ws_size;

    const int N0 = 131072, N1 = 32768, N2 = 8192, N3 = 2048, N4 = 512, N5 = 256;

    const float* x      = (const float*)d_in[0];
    const float* w_mlp1 = (const float*)d_in[1];
    const float* g_mlp1 = (const float*)d_in[2];
    const float* b_mlp1 = (const float*)d_in[3];
    const float* w_c[6]; const float* g_c[6]; const float* b_c[6];
    for (int i = 0; i < 6; i++) {
        w_c[i] = (const float*)d_in[4 + 3 * i];
        g_c[i] = (const float*)d_in[5 + 3 * i];
        b_c[i] = (const float*)d_in[6 + 3 * i];
    }
    const float* w_d[5]; const float* g_d[5]; const float* b_d[5];
    for (int i = 0; i < 5; i++) {
        w_d[i] = (const float*)d_in[22 + 3 * i];
        g_d[i] = (const float*)d_in[23 + 3 * i];
        b_d[i] = (const float*)d_in[24 + 3 * i];
    }
    const float* w_f1 = (const float*)d_in[37];
    const float* g_f1 = (const float*)d_in[38];
    const float* b_f1 = (const float*)d_in[39];
    const float* w_f2 = (const float*)d_in[40];
    const float* g_f2 = (const float*)d_in[41];
    const float* b_f2 = (const float*)d_in[42];
    const float* w_f3 = (const float*)d_in[43];
    const float* bias_f3 = (const float*)d_in[44];
    const int* nbr[6];
    for (int i = 0; i < 6; i++) nbr[i] = (const int*)d_in[45 + i];
    const int* pool[5];
    for (int i = 0; i < 5; i++) pool[i] = (const int*)d_in[51 + i];

    float* ws    = (float*)d_ws;
    float* bufA  = ws;                    // y buffers / fc outs (2.10M floats)
    float* bufB  = bufA + 2097152;        // conv finals + partial arena (8.39M w/ bufC)
    float* bufC  = bufB + 4194304;        // down raw / z / partial overflow
    float* stats = bufC + 4194304;        // 14 * 1024
    float* out = (float*)d_out;

    auto st = [&](int slot) { return stats + slot * 1024; };
    auto run_stats = [&](const float* buf, int total, int C, int bs, int slot) {
        int total4 = total / 4, C4 = C / 4;
        int gr = (total4 + bs - 1) / bs;
        if (gr > 768) gr = 768;
        stats4_kernel<<<gr, bs, 0, stream>>>((const float4*)buf, total4, C, C4, st(slot));
    };

    const float iN0 = 1.f / N0, iN1 = 1.f / N1, iN2 = 1.f / N2, iN3 = 1.f / N3,
                iN4 = 1.f / N4, iN5 = 1.f / N5, i8 = 1.f / 8.f;

    zero_kernel<<<56, 256, 0, stream>>>(stats, 14 * 1024);

    // ---- mlp1 raw -> bufA; stats slot 0
    mlp1_kernel<<<N0 / 256, 256, 0, stream>>>(x, w_mlp1, bufA, N0);
    run_stats(bufA, N0 * 16, 16, 256, 0);

    // ---- level 0: conv1 16->32 (PREF lookahead, norm-in, fused stats slot1)
    convd_kernel<16, 32, 32, 1, 1024, 128, 256, 2, 27, true, true, true>
        <<<1024, 256, 0, stream>>>(bufA, nbr[0], w_c[0], bufB,
                                   st(0), g_mlp1, b_mlp1, iN0, st(1));
    down3_kernel<16, 32, 32, 2, 256, true>
        <<<1024, 256, 0, stream>>>(bufA, bufB, w_d[0], bufC,
                                   st(0), g_mlp1, b_mlp1, iN0,
                                   st(1), g_c[0], b_c[0], iN0, st(2));
    pool2_kernel<32, 256><<<N1 * 8 / 256, 256, 0, stream>>>(
        bufC, pool[0], st(2), g_d[0], b_d[0], iN0, bufA, N1);

    // ---- level 1: conv2 32->48, ks=3 (KT=9), partials in bufB arena
    convd_kernel<32, 48, 48, 1, 512, 64, 192, 2, 9, false, false, false>
        <<<1536, 192, 0, stream>>>(bufA, nbr[1], w_c[1], bufB,
                                   nullptr, nullptr, nullptr, 0.f, nullptr);
    reducek_kernel<48, 3><<<1024, 192, 0, stream>>>(
        (const float4*)bufB, (float4*)bufB, N1 * 12, st(3));
    down3_kernel<32, 48, 48, 2, 192, false>
        <<<512, 192, 0, stream>>>(bufA, bufB, w_d[1], bufC,
                                  nullptr, nullptr, nullptr, 0.f,
                                  st(3), g_c[1], b_c[1], iN1, st(4));
    pool2_kernel<48, 192><<<N2 * 12 / 192, 192, 0, stream>>>(
        bufC, pool[1], st(4), g_d[1], b_d[1], iN1, bufA, N2);

    // ---- level 2: conv3 48->96, NCOT=2, ks=9 (KT=3)
    convd_kernel<48, 96, 48, 2, 128, 64, 192, 2, 3, false, false, false>
        <<<2304, 192, 0, stream>>>(bufA, nbr[2], w_c[2], bufB,
                                   nullptr, nullptr, nullptr, 0.f, nullptr);
    reducek_kernel<96, 9><<<1024, 192, 0, stream>>>(
        (const float4*)bufB, (float4*)bufB, N2 * 24, st(5));
    down3_kernel<48, 96, 96, 2, 192, false>
        <<<256, 192, 0, stream>>>(bufA, bufB, w_d[2], bufC,
                                  nullptr, nullptr, nullptr, 0.f,
                                  st(5), g_c[2], b_c[2], iN2, st(6));
    pool2_kernel<96, 192><<<N3 * 24 / 192, 192, 0, stream>>>(
        bufC, pool[2], st(6), g_d[2], b_d[2], iN2, bufA, N3);

    // ---- level 3: conv4 96->128, NCOT=2, ks=27 (KT=1)
    convd_kernel<96, 128, 64, 2, 32, 64, 256, 2, 1, false, false, false>
        <<<1728, 256, 0, stream>>>(bufA, nbr[3], w_c[3], bufB,
                                   nullptr, nullptr, nullptr, 0.f, nullptr);
    reducek_kernel<128, 27><<<256, 256, 0, stream>>>(
        (const float4*)bufB, (float4*)bufB, N3 * 32, st(7));
    down3_kernel<96, 128, 128, 2, 256, false>
        <<<64, 256, 0, stream>>>(bufA, bufB, w_d[3], bufC,
                                 nullptr, nullptr, nullptr, 0.f,
                                 st(7), g_c[3], b_c[3], iN3, st(8));
    pool2_kernel<128, 256><<<N4 * 32 / 256, 256, 0, stream>>>(
        bufC, pool[3], st(8), g_d[3], b_d[3], iN3, bufA, N4);

    // ---- level 4: conv5 128->256, NCOT=4, ks=27
    convd_kernel<128, 256, 64, 4, 8, 64, 256, 2, 1, false, false, false>
        <<<864, 256, 0, stream>>>(bufA, nbr[4], w_c[4], bufB,
                                  nullptr, nullptr, nullptr, 0.f, nullptr);
    reducek_kernel<256, 27><<<128, 256, 0, stream>>>(
        (const float4*)bufB, (float4*)bufB, N4 * 64, st(9));
    down3_kernel<128, 256, 256, 2, 256, false>
        <<<32, 256, 0, stream>>>(bufA, bufB, w_d[4], bufC,
                                 nullptr, nullptr, nullptr, 0.f,
                                 st(9), g_c[4], b_c[4], iN4, st(10));
    pool2_kernel<256, 256><<<N5 * 64 / 256, 256, 0, stream>>>(
        bufC, pool[4], st(10), g_d[4], b_d[4], iN4, bufA, N5);

    // ---- conv6 256->512, NCOT=8, ks=27
    convd_kernel<256, 512, 64, 8, 4, 64, 256, 2, 1, false, false, false>
        <<<864, 256, 0, stream>>>(bufA, nbr[5], w_c[5], bufB,
                                  nullptr, nullptr, nullptr, 0.f, nullptr);
    reducek_kernel<512, 27><<<128, 256, 0, stream>>>(
        (const float4*)bufB, (float4*)bufB, N5 * 128, st(11));

    // ---- segment pooling (applies conv6 BN) -> z in bufC
    segpool2_kernel<<<8, 512, 0, stream>>>(bufB, st(11), g_c[5], b_c[5], iN5, bufC);

    // ---- f1: z @ w_f1 raw -> bufA
    zero_kernel<<<16, 256, 0, stream>>>(bufA, 4096);
    fc_kernel<1024, 512, 4, false><<<dim3(8, 4), 256, 0, stream>>>(
        bufC, w_f1, nullptr, nullptr, nullptr, 0.f, bufA);
    run_stats(bufA, 8 * 512, 512, 256, 12);

    // ---- f2: normalize(f1) @ w_f2 raw -> bufB
    zero_kernel<<<8, 256, 0, stream>>>(bufB, 2048);
    fc_kernel<512, 256, 4, true><<<dim3(4, 4), 256, 0, stream>>>(
        bufA, w_f2, st(12), g_f1, b_f1, i8, bufB);
    run_stats(bufB, 8 * 256, 256, 256, 13);

    // ---- f3
    f3n_kernel<<<1, 256, 0, stream>>>(bufB, w_f3, bias_f3, st(13), g_f2, b_f2, i8, out);
}